// Round 1
// 414.661 us; speedup vs baseline: 1.0123x; 1.0123x over previous
//
#include <hip/hip_runtime.h>
#include <hip/hip_bf16.h>
#include <math.h>

// Problem constants
constexpr int cB   = 4;
constexpr int cL   = 1024;
constexpr int cH   = 1024;
constexpr int cA   = 16;
constexpr int cM   = 128;
constexpr int cE   = 32;
constexpr int cR   = 992;
constexpr int cEMB = 768;
constexpr int cC   = 97;
constexpr int cN   = cB * cR;   // 3968

typedef unsigned short ushort;
typedef __attribute__((ext_vector_type(4))) unsigned short ushort4v;
typedef __attribute__((ext_vector_type(8))) short short8;
typedef __attribute__((ext_vector_type(4))) float float4v;

static __device__ inline float bf2f(ushort u) {
    unsigned v = ((unsigned)u) << 16;
    float f;
    __builtin_memcpy(&f, &v, 4);
    return f;
}
static __device__ inline ushort f2bf(float f) {
    unsigned u;
    __builtin_memcpy(&u, &f, 4);
    unsigned r = (u + 0x7FFFu + ((u >> 16) & 1u)) >> 16;
    return (ushort)r;
}

// ---------------------------------------------------------------------------
// Generic transpose f32 -> bf16: src[z][R][C] -> dst[z][Cp][R], zero-pad c>=C
__global__ void tr_bf16_k(const float* __restrict__ src, ushort* __restrict__ dst,
                          int R, int C, int Cp) {
    int z = blockIdx.z;
    int r0 = blockIdx.x * 32, c0 = blockIdx.y * 32;
    int tx = threadIdx.x & 31, ty = threadIdx.x >> 5;  // ty 0..7
    __shared__ float tile[32][33];
    for (int p = 0; p < 4; p++) {
        int r = r0 + ty + p * 8, c = c0 + tx;
        tile[ty + p * 8][tx] = (r < R && c < C) ? src[((size_t)z * R + r) * C + c] : 0.f;
    }
    __syncthreads();
    for (int p = 0; p < 4; p++) {
        int c = c0 + ty + p * 8, r = r0 + tx;
        if (c < Cp && r < R)
            dst[((size_t)z * Cp + c) * R + r] = f2bf(tile[tx][ty + p * 8]);
    }
}

// Head+tail weight transpose in one launch (z selects which matrix)
__global__ void tr_ht_k(const float* __restrict__ Wh, const float* __restrict__ Wt,
                        ushort* __restrict__ WTh, ushort* __restrict__ WTt) {
    const float* src = blockIdx.z ? Wt : Wh;
    ushort* dst = blockIdx.z ? WTt : WTh;
    int r0 = blockIdx.x * 32, c0 = blockIdx.y * 32;
    int tx = threadIdx.x & 31, ty = threadIdx.x >> 5;
    __shared__ float tile[32][33];
    for (int p = 0; p < 4; p++) {
        int r = r0 + ty + p * 8, c = c0 + tx;
        tile[ty + p * 8][tx] = src[(size_t)r * cEMB + c];
    }
    __syncthreads();
    for (int p = 0; p < 4; p++) {
        int c = c0 + ty + p * 8, r = r0 + tx;
        dst[(size_t)c * (2 * cH) + r] = f2bf(tile[tx][ty + p * 8]);
    }
}

// ---------------------------------------------------------------------------
// Build fragment-ordered bilinear weights (16 frags per i, v3 layout):
// Wf[si][f][lane][8] bf16, f = khalf*8+ct,
// element = W[(si*64 + j)][c], j = khalf*32 + (lane>>4)*8 + jj, c = ct*16 + (lane&15)
__global__ void wf_build_k(const float* __restrict__ W, ushort* __restrict__ Wf) {
    const int si = blockIdx.x;
    const int tid = threadIdx.x;
    __shared__ ushort sWb[64 * 136];
    for (int idx = tid; idx < 64 * 128; idx += 256) {
        int r = idx >> 7, c = idx & 127;
        float v = (c < cC) ? W[((size_t)si * 64 + r) * cC + c] : 0.f;
        sWb[r * 136 + c] = f2bf(v);
    }
    __syncthreads();
#pragma unroll
    for (int p = 0; p < 4; p++) {
        int e = tid + p * 256;          // 0..1023
        int f = e >> 6, lane = e & 63;
        int g = lane >> 4, col = lane & 15;
        int khalf = f >> 3, ct = f & 7;
        int jb = khalf * 32 + g * 8;
        int c = ct * 16 + col;
        short8 v;
#pragma unroll
        for (int jj = 0; jj < 8; jj++) v[jj] = (short)sWb[(jb + jj) * 136 + c];
        *(short8*)&Wf[(((size_t)si * 16 + f) * 64 + lane) * 8] = v;
    }
}

// ---------------------------------------------------------------------------
// Kernel 1: per-(b,e) logsumexp pooling of ent_lhs; writes bf16.
__global__ void ent_pool_k(const float* __restrict__ ent_lhs, const int* __restrict__ ids,
                           ushort* __restrict__ ent_emb, int* __restrict__ counts) {
    int e = blockIdx.x, b = blockIdx.y;
    __shared__ int sid[cM];
    int tid = threadIdx.x;
    if (tid < cM) sid[tid] = ids[b * cM + tid];
    __syncthreads();
    int cnt = 0;
    for (int m = 0; m < cM; m++) cnt += (sid[m] == e) ? 1 : 0;
    if (blockIdx.z == 0 && tid == 0) counts[b * cE + e] = cnt;
    int h = blockIdx.z * 256 + tid;
    {
        float mx = -1e30f;
        for (int m = 0; m < cM; m++)
            if (sid[m] == e) mx = fmaxf(mx, ent_lhs[(size_t)(b * cM + m) * cH + h]);
        float s = 0.f;
        for (int m = 0; m < cM; m++)
            if (sid[m] == e) s += __expf(ent_lhs[(size_t)(b * cM + m) * cH + h] - mx);
        ent_emb[(size_t)(b * cE + e) * cH + h] = f2bf((cnt > 0) ? (mx + __logf(s)) : 0.f);
    }
}

// ---------------------------------------------------------------------------
// Kernel 2: ent_attn[b][e][a][l] (bf16) = segment-mean of attn
__global__ void ent_attn_k(const float* __restrict__ attn, const int* __restrict__ ids,
                           const int* __restrict__ counts, ushort* __restrict__ ent_attn) {
    int ba = blockIdx.x;
    int b = ba / cA, a = ba % cA;
    int tid = threadIdx.x;
    int l = blockIdx.y * 256 + tid;
    __shared__ int sid[cM];
    __shared__ int scnt[cE];
    __shared__ float sacc[256 * 33];
    if (tid < cM) sid[tid] = ids[b * cM + tid];
    if (tid < cE) scnt[tid] = counts[b * cE + tid];
    float* acc = &sacc[tid * 33];
    for (int e2 = 0; e2 < cE; e2++) acc[e2] = 0.f;
    __syncthreads();
    const float* ap = attn + ((size_t)(b * cA + a) * cM) * cL + l;
    for (int m = 0; m < cM; m++) acc[sid[m]] += ap[(size_t)m * cL];
    for (int e2 = 0; e2 < cE; e2++) {
        ent_attn[((size_t)(b * cE + e2) * cA + a) * cL + l] =
            f2bf(acc[e2] / (float)max(scnt[e2], 1));
    }
}

// ---------------------------------------------------------------------------
// Kernel 3: w[b][r][l] = mean_a ha*ta, normalized over l (ushort4 vectorized)
__global__ void w_k(const ushort* __restrict__ ent_attn, const int* __restrict__ hts,
                    ushort* __restrict__ w) {
    int nr = blockIdx.x;
    int b = nr / cR;
    int he = hts[nr * 2 + 0], te = hts[nr * 2 + 1];
    int tid = threadIdx.x;
    int l0 = tid * 4;
    const ushort* ha = ent_attn + ((size_t)(b * cE + he) * cA) * cL + l0;
    const ushort* ta = ent_attn + ((size_t)(b * cE + te) * cA) * cL + l0;
    float v[4] = {0.f, 0.f, 0.f, 0.f};
#pragma unroll
    for (int a = 0; a < cA; a++) {
        ushort4v hv = *(const ushort4v*)&ha[(size_t)a * cL];
        ushort4v tv = *(const ushort4v*)&ta[(size_t)a * cL];
#pragma unroll
        for (int i = 0; i < 4; i++) v[i] += bf2f(hv[i]) * bf2f(tv[i]);
    }
    float psum = 0.f;
#pragma unroll
    for (int i = 0; i < 4; i++) { v[i] *= (1.0f / cA); psum += v[i]; }
    for (int off = 32; off > 0; off >>= 1) psum += __shfl_down(psum, off, 64);
    __shared__ float red[4];
    if ((tid & 63) == 0) red[tid >> 6] = psum;
    __syncthreads();
    float tot = red[0] + red[1] + red[2] + red[3];
    float inv = 1.0f / (tot + 1e-5f);
    ushort4v o;
#pragma unroll
    for (int i = 0; i < 4; i++) o[i] = f2bf(v[i] * inv);
    *(ushort4v*)&w[(size_t)nr * cL + l0] = o;
}

// ---------------------------------------------------------------------------
// Kernel 4: rel MFMA GEMM: rel[n][h] = sum_l w[n][l] * seqT[b][h][l]
__global__ __launch_bounds__(256) void
rel_mfma_k(const ushort* __restrict__ wbf, const ushort* __restrict__ seqT,
           ushort* __restrict__ relbf) {
    const int b = blockIdx.z;
    const int r0 = blockIdx.x * 128, h0 = blockIdx.y * 64;
    const int tid = threadIdx.x, lane = tid & 63, wv = tid >> 6;
    const int col = lane & 15, g = lane >> 4;

    __shared__ ushort sA[128 * 72];
    __shared__ ushort sB[64 * 72];

    float4v acc[2][4];
#pragma unroll
    for (int mt = 0; mt < 2; mt++)
#pragma unroll
        for (int ct = 0; ct < 4; ct++) acc[mt][ct] = (float4v){0.f, 0.f, 0.f, 0.f};

    for (int kt = 0; kt < cL; kt += 64) {
#pragma unroll
        for (int p = 0; p < 4; p++) {
            int t = tid + p * 256;
            int row = t >> 3, seg = t & 7;
            int r = min(r0 + row, cR - 1);
            *(short8*)&sA[row * 72 + seg * 8] =
                *(const short8*)&wbf[((size_t)b * cR + r) * cL + kt + seg * 8];
        }
#pragma unroll
        for (int p = 0; p < 2; p++) {
            int t = tid + p * 256;
            int c = t >> 3, seg = t & 7;
            *(short8*)&sB[c * 72 + seg * 8] =
                *(const short8*)&seqT[((size_t)b * cH + h0 + c) * cL + kt + seg * 8];
        }
        __syncthreads();
        const int wrow = wv * 32;
#pragma unroll
        for (int k0 = 0; k0 < 64; k0 += 32) {
            short8 a0 = *(const short8*)&sA[(wrow + col) * 72 + k0 + g * 8];
            short8 a1 = *(const short8*)&sA[(wrow + 16 + col) * 72 + k0 + g * 8];
#pragma unroll
            for (int ct = 0; ct < 4; ct++) {
                short8 bf = *(const short8*)&sB[(ct * 16 + col) * 72 + k0 + g * 8];
                acc[0][ct] = __builtin_amdgcn_mfma_f32_16x16x32_bf16(a0, bf, acc[0][ct], 0, 0, 0);
                acc[1][ct] = __builtin_amdgcn_mfma_f32_16x16x32_bf16(a1, bf, acc[1][ct], 0, 0, 0);
            }
        }
        __syncthreads();
    }
#pragma unroll
    for (int mt = 0; mt < 2; mt++) {
#pragma unroll
        for (int ct = 0; ct < 4; ct++) {
            int h = h0 + ct * 16 + col;
            int rowb = r0 + wv * 32 + mt * 16 + g * 4;
#pragma unroll
            for (int reg = 0; reg < 4; reg++) {
                int r = rowb + reg;
                if (r < cR)
                    relbf[((size_t)b * cR + r) * cH + h] = f2bf(acc[mt][ct][reg]);
            }
        }
    }
}

// ---------------------------------------------------------------------------
// Kernel 5: projection MFMA GEMM, head+tail fused (blockIdx.z = sel).
__global__ __launch_bounds__(256) void
proj_mfma_k(const ushort* __restrict__ ent_bf, const ushort* __restrict__ relbf,
            const int* __restrict__ hts,
            const ushort* __restrict__ WTh, const ushort* __restrict__ WTt,
            const float* __restrict__ head_b, const float* __restrict__ tail_b,
            ushort* __restrict__ hsp, ushort* __restrict__ tsp) {
    const int sel = blockIdx.z;
    const ushort* WTp = sel ? WTt : WTh;
    const float* bias = sel ? tail_b : head_b;
    ushort* outp = sel ? tsp : hsp;

    const int n0 = blockIdx.x * 64, e0 = blockIdx.y * 64;
    const int tid = threadIdx.x, lane = tid & 63, wv = tid >> 6;
    const int col = lane & 15, g = lane >> 4;

    __shared__ int sbase[64];
    __shared__ ushort sA[64 * 72];
    __shared__ ushort sB[64 * 72];

    if (tid < 64) {
        int n = n0 + tid, bb = n / cR;
        sbase[tid] = (bb * cE + hts[n * 2 + sel]) * cH;
    }
    __syncthreads();

    float4v acc[4];
#pragma unroll
    for (int ct = 0; ct < 4; ct++) acc[ct] = (float4v){0.f, 0.f, 0.f, 0.f};

    for (int kt = 0; kt < 2 * cH; kt += 64) {
        const bool first = kt < cH;
#pragma unroll
        for (int p = 0; p < 2; p++) {
            int t = tid + p * 256;
            int row = t >> 3, seg = t & 7;
            const ushort* src = first
                ? &ent_bf[(size_t)sbase[row] + kt + seg * 8]
                : &relbf[(size_t)(n0 + row) * cH + (kt - cH) + seg * 8];
            *(short8*)&sA[row * 72 + seg * 8] = *(const short8*)src;
        }
#pragma unroll
        for (int p = 0; p < 2; p++) {
            int t = tid + p * 256;
            int c = t >> 3, seg = t & 7;
            *(short8*)&sB[c * 72 + seg * 8] =
                *(const short8*)&WTp[(size_t)(e0 + c) * (2 * cH) + kt + seg * 8];
        }
        __syncthreads();
        const int wrow = wv * 16;
#pragma unroll
        for (int k0 = 0; k0 < 64; k0 += 32) {
            short8 a0 = *(const short8*)&sA[(wrow + col) * 72 + k0 + g * 8];
#pragma unroll
            for (int ct = 0; ct < 4; ct++) {
                short8 bf = *(const short8*)&sB[(ct * 16 + col) * 72 + k0 + g * 8];
                acc[ct] = __builtin_amdgcn_mfma_f32_16x16x32_bf16(a0, bf, acc[ct], 0, 0, 0);
            }
        }
        __syncthreads();
    }
#pragma unroll
    for (int ct = 0; ct < 4; ct++) {
        int e = e0 + ct * 16 + col;
        float bv = bias[e];
        int rowb = n0 + wv * 16 + g * 4;
#pragma unroll
        for (int reg = 0; reg < 4; reg++)
            outp[(size_t)(rowb + reg) * cEMB + e] = f2bf(tanhf(acc[ct][reg] + bv));
    }
}

// ---------------------------------------------------------------------------
// Kernel 6a: out init with bias
__global__ void out_init_k(const float* __restrict__ bil_b, float* __restrict__ out) {
    int idx = blockIdx.x * 256 + threadIdx.x;
    if (idx < cN * cC) out[idx] = bil_b[idx % cC];
}

// ---------------------------------------------------------------------------
// async stage of one Wf i-block (16 KB, frag-major linear) into LDS.
// Layout is exactly wave-uniform-base + lane*16: wave wv copies bytes
// [wv*4096 + p*1024, +1KB) of the block; HW adds lane*16 on the LDS side,
// the global source carries the matching lane*16 (lane*8 ushorts).
static __device__ inline void stage_wf(const ushort* __restrict__ WfS, int i,
                                       ushort* dstbase, int wv, int lane) {
#pragma unroll
    for (int p = 0; p < 4; p++) {
        const ushort* src = WfS + (size_t)i * 8192 + wv * 2048 + p * 512 + lane * 8;
        ushort* dst = dstbase + wv * 2048 + p * 512;
        __builtin_amdgcn_global_load_lds(
            (const __attribute__((address_space(1))) unsigned int*)src,
            (__attribute__((address_space(3))) unsigned int*)dst, 16, 0, 0);
    }
}

// ---------------------------------------------------------------------------
// Kernel 6b: bilinear v8. v7's register double-buffer of W-fragments is
// replaced by an LDS double buffer filled with global_load_lds (width=16).
// Rationale (rocprof on v7): MfmaUtil 15.8 / VALUBusy 19 / HBM 7% — pure
// latency exposure. v7's per-wave global fetch of 8 frags/i with depth-1
// register prefetch (~300cy cover vs 220-900cy L2/L3 latency) stalled every
// half-iter, and waves (0,2)/(1,3) fetched identical frags (2x global
// traffic). v8: one 16KB Wf[i] block staged per step by all 4 waves
// (async DMA, no VGPR round-trip), waves share it via LDS broadcast.
// One barrier per step: the compiler's vmcnt(0)-drain before s_barrier is
// exactly the ready-point for buffer i+1. ds_read_b128 at lane-stride 16B
// is bank-conflict-free. Frees the 64 w0/w1 VGPRs (expect ~3 waves/SIMD),
// LDS 49664B -> 3 blocks/CU, 744 blocks all co-resident.
__global__ __launch_bounds__(256) void
bil_mfma8_k(const ushort* __restrict__ hsp, const ushort* __restrict__ tsp,
            const ushort* __restrict__ Wf, float* __restrict__ out) {
    const int islice = blockIdx.x;       // 0..23
    const int n0 = blockIdx.y * 128;
    const int kb = islice >> 1;          // ts column block
    const int tid = threadIdx.x;
    const int lane = tid & 63, wv = tid >> 6;
    const int col = lane & 15, g = lane >> 4;
    const int rh = wv >> 1, cth = wv & 1;

    __shared__ float sHs[32 * 132];      // [i][row]
    __shared__ ushort sW[2][8192];       // double-buffered Wf[i] (16 KB each)

    // stage hs tile -> f32 LDS, transposed
    for (int idx = tid; idx < 512; idx += 256) {
        int row = idx & 127, seg = idx >> 7;
        short8 v = *(const short8*)&hsp[(size_t)(n0 + row) * cEMB + islice * 32 + seg * 8];
#pragma unroll
        for (int jj = 0; jj < 8; jj++)
            sHs[(seg * 8 + jj) * 132 + row] = bf2f((ushort)v[jj]);
    }

    // ts A-fragments (held in registers for all 32 iterations)
    short8 tsA[4][2];
#pragma unroll
    for (int mt = 0; mt < 4; mt++)
#pragma unroll
        for (int kh = 0; kh < 2; kh++)
            tsA[mt][kh] = *(const short8*)
                &tsp[(size_t)(n0 + rh * 64 + mt * 16 + col) * cEMB + kb * 64 + kh * 32 + g * 8];

    float4v acc[4][4];
#pragma unroll
    for (int mt = 0; mt < 4; mt++)
#pragma unroll
        for (int ct = 0; ct < 4; ct++) acc[mt][ct] = (float4v){0.f, 0.f, 0.f, 0.f};

    const ushort* WfS = Wf + (size_t)islice * 32 * 8192;

    stage_wf(WfS, 0, &sW[0][0], wv, lane);
    __syncthreads();   // sHs written + sW[0] landed (vmcnt/lgkm drained at barrier)

    for (int i = 0; i < 32; ++i) {
        const ushort* sWb = &sW[i & 1][0];
        if (i + 1 < 32) stage_wf(WfS, i + 1, &sW[(i + 1) & 1][0], wv, lane);

        // W fragments for this wave: f = kh*8 + cth*4 + ctl, 16B per lane
        short8 wfr[2][4];
#pragma unroll
        for (int kh = 0; kh < 2; kh++)
#pragma unroll
            for (int ctl = 0; ctl < 4; ctl++)
                wfr[kh][ctl] = *(const short8*)
                    &sWb[((kh * 8 + cth * 4 + ctl) * 64 + lane) * 8];

        float4v hsv[4];
#pragma unroll
        for (int mt = 0; mt < 4; mt++)
            hsv[mt] = *(const float4v*)&sHs[i * 132 + rh * 64 + mt * 16 + g * 4];

#pragma unroll
        for (int ctl = 0; ctl < 4; ctl++) {
#pragma unroll
            for (int mt = 0; mt < 4; mt++) {
                float4v P = (float4v){0.f, 0.f, 0.f, 0.f};
                P = __builtin_amdgcn_mfma_f32_16x16x32_bf16(tsA[mt][0], wfr[0][ctl], P, 0, 0, 0);
                P = __builtin_amdgcn_mfma_f32_16x16x32_bf16(tsA[mt][1], wfr[1][ctl], P, 0, 0, 0);
                acc[mt][ctl] += hsv[mt] * P;
            }
        }
        __syncthreads();  // all waves done reading sW[i&1]; sW[(i+1)&1] landed
    }

    // epilogue: atomic combine over 24 slices
#pragma unroll
    for (int mt = 0; mt < 4; mt++) {
#pragma unroll
        for (int ctl = 0; ctl < 4; ctl++) {
            int c = (cth * 4 + ctl) * 16 + col;
            if (c < cC) {
                int rowb = n0 + rh * 64 + mt * 16 + g * 4;
#pragma unroll
                for (int reg = 0; reg < 4; reg++)
                    atomicAdd(&out[(size_t)(rowb + reg) * cC + c], acc[mt][ctl][reg]);
            }
        }
    }
}

// ---------------------------------------------------------------------------
extern "C" void kernel_launch(void* const* d_in, const int* in_sizes, int n_in,
                              void* d_out, int out_size, void* d_ws, size_t ws_size,
                              hipStream_t stream) {
    const float* seq_lhs  = (const float*)d_in[0];
    const float* ent_lhs  = (const float*)d_in[1];
    const float* attn     = (const float*)d_in[2];
    const int*   ids      = (const int*)d_in[3];
    const int*   hts      = (const int*)d_in[4];
    const float* head_W   = (const float*)d_in[5];
    const float* head_b   = (const float*)d_in[6];
    const float* tail_W   = (const float*)d_in[7];
    const float* tail_b   = (const float*)d_in[8];
    const float* bil_W    = (const float*)d_in[9];
    const float* bil_b    = (const float*)d_in[10];
    float* out = (float*)d_out;

    // workspace layout (byte offsets, 256B-aligned)
    char* ws = (char*)d_ws;
    int*    counts   = (int*)(ws + 0);             // 512 B
    ushort* ent_bf   = (ushort*)(ws + 512);        // 262144 B
    ushort* ent_attn = (ushort*)(ws + 262656);     // bf16, 4194304 B
    ushort* wbuf     = (ushort*)(ws + 4456960);    // 8126464 B
    ushort* relbf    = (ushort*)(ws + 12583424);   // 8126464 B
    ushort* hsp      = (ushort*)(ws + 20709888);   // 6094848 B
    ushort* tsp      = (ushort*)(ws + 26804736);   // 6094848 B
    ushort* Wf       = (ushort*)(ws + 32899584);   // 12582912 B
    ushort* WTh      = (ushort*)(ws + 45482496);   // 3145728 B
    ushort* WTt      = (ushort*)(ws + 48628224);   // 3145728 B
    ushort* seqT     = (ushort*)(ws + 51773952);   // 8388608 B  (end 60162560)

    hipLaunchKernelGGL(wf_build_k, dim3(768), dim3(256), 0, stream, bil_W, Wf);
    hipLaunchKernelGGL(tr_ht_k, dim3(64, 24, 2), dim3(256), 0, stream,
                       head_W, tail_W, WTh, WTt);
    hipLaunchKernelGGL(tr_bf16_k, dim3(32, 32, cB), dim3(256), 0, stream,
                       seq_lhs, seqT, cL, cH, cH);

    hipLaunchKernelGGL(ent_pool_k, dim3(cE, cB, 4), dim3(256), 0, stream,
                       ent_lhs, ids, ent_bf, counts);
    hipLaunchKernelGGL(ent_attn_k, dim3(cB * cA, cL / 256), dim3(256), 0, stream,
                       attn, ids, counts, ent_attn);
    hipLaunchKernelGGL(w_k, dim3(cN), dim3(256), 0, stream,
                       ent_attn, hts, wbuf);
    hipLaunchKernelGGL(rel_mfma_k, dim3(8, 16, cB), dim3(256), 0, stream,
                       wbuf, seqT, relbf);
    hipLaunchKernelGGL(proj_mfma_k, dim3(cN / 64, cEMB / 64, 2), dim3(256), 0, stream,
                       ent_bf, relbf, hts, WTh, WTt, head_b, tail_b, hsp, tsp);
    hipLaunchKernelGGL(out_init_k, dim3((cN * cC + 255) / 256), dim3(256), 0, stream,
                       bil_b, out);
    hipLaunchKernelGGL(bil_mfma8_k, dim3(24, cN / 128), dim3(256), 0, stream,
                       hsp, tsp, Wf, out);
}

// Round 2
// 405.525 us; speedup vs baseline: 1.0351x; 1.0225x over previous
//
#include <hip/hip_runtime.h>
#include <hip/hip_bf16.h>
#include <math.h>

// Problem constants
constexpr int cB   = 4;
constexpr int cL   = 1024;
constexpr int cH   = 1024;
constexpr int cA   = 16;
constexpr int cM   = 128;
constexpr int cE   = 32;
constexpr int cR   = 992;
constexpr int cEMB = 768;
constexpr int cC   = 97;
constexpr int cN   = cB * cR;   // 3968
constexpr int cNG  = 8;         // islice groups (3 islices each)

typedef unsigned short ushort;
typedef __attribute__((ext_vector_type(4))) unsigned short ushort4v;
typedef __attribute__((ext_vector_type(8))) short short8;
typedef __attribute__((ext_vector_type(4))) float float4v;

static __device__ inline float bf2f(ushort u) {
    unsigned v = ((unsigned)u) << 16;
    float f;
    __builtin_memcpy(&f, &v, 4);
    return f;
}
static __device__ inline ushort f2bf(float f) {
    unsigned u;
    __builtin_memcpy(&u, &f, 4);
    unsigned r = (u + 0x7FFFu + ((u >> 16) & 1u)) >> 16;
    return (ushort)r;
}

// ---------------------------------------------------------------------------
// Generic transpose f32 -> bf16: src[z][R][C] -> dst[z][Cp][R], zero-pad c>=C
__global__ void tr_bf16_k(const float* __restrict__ src, ushort* __restrict__ dst,
                          int R, int C, int Cp) {
    int z = blockIdx.z;
    int r0 = blockIdx.x * 32, c0 = blockIdx.y * 32;
    int tx = threadIdx.x & 31, ty = threadIdx.x >> 5;  // ty 0..7
    __shared__ float tile[32][33];
    for (int p = 0; p < 4; p++) {
        int r = r0 + ty + p * 8, c = c0 + tx;
        tile[ty + p * 8][tx] = (r < R && c < C) ? src[((size_t)z * R + r) * C + c] : 0.f;
    }
    __syncthreads();
    for (int p = 0; p < 4; p++) {
        int c = c0 + ty + p * 8, r = r0 + tx;
        if (c < Cp && r < R)
            dst[((size_t)z * Cp + c) * R + r] = f2bf(tile[tx][ty + p * 8]);
    }
}

// Head+tail weight transpose in one launch (z selects which matrix)
__global__ void tr_ht_k(const float* __restrict__ Wh, const float* __restrict__ Wt,
                        ushort* __restrict__ WTh, ushort* __restrict__ WTt) {
    const float* src = blockIdx.z ? Wt : Wh;
    ushort* dst = blockIdx.z ? WTt : WTh;
    int r0 = blockIdx.x * 32, c0 = blockIdx.y * 32;
    int tx = threadIdx.x & 31, ty = threadIdx.x >> 5;
    __shared__ float tile[32][33];
    for (int p = 0; p < 4; p++) {
        int r = r0 + ty + p * 8, c = c0 + tx;
        tile[ty + p * 8][tx] = src[(size_t)r * cEMB + c];
    }
    __syncthreads();
    for (int p = 0; p < 4; p++) {
        int c = c0 + ty + p * 8, r = r0 + tx;
        dst[(size_t)c * (2 * cH) + r] = f2bf(tile[tx][ty + p * 8]);
    }
}

// ---------------------------------------------------------------------------
// Build fragment-ordered bilinear weights (16 frags per i, v3 layout):
// Wf[si][f][lane][8] bf16, f = khalf*8+ct,
// element = W[(si*64 + j)][c], j = khalf*32 + (lane>>4)*8 + jj, c = ct*16 + (lane&15)
__global__ void wf_build_k(const float* __restrict__ W, ushort* __restrict__ Wf) {
    const int si = blockIdx.x;
    const int tid = threadIdx.x;
    __shared__ ushort sWb[64 * 136];
    for (int idx = tid; idx < 64 * 128; idx += 256) {
        int r = idx >> 7, c = idx & 127;
        float v = (c < cC) ? W[((size_t)si * 64 + r) * cC + c] : 0.f;
        sWb[r * 136 + c] = f2bf(v);
    }
    __syncthreads();
#pragma unroll
    for (int p = 0; p < 4; p++) {
        int e = tid + p * 256;          // 0..1023
        int f = e >> 6, lane = e & 63;
        int g = lane >> 4, col = lane & 15;
        int khalf = f >> 3, ct = f & 7;
        int jb = khalf * 32 + g * 8;
        int c = ct * 16 + col;
        short8 v;
#pragma unroll
        for (int jj = 0; jj < 8; jj++) v[jj] = (short)sWb[(jb + jj) * 136 + c];
        *(short8*)&Wf[(((size_t)si * 16 + f) * 64 + lane) * 8] = v;
    }
}

// ---------------------------------------------------------------------------
// Kernel 1: per-(b,e) logsumexp pooling of ent_lhs; writes bf16.
__global__ void ent_pool_k(const float* __restrict__ ent_lhs, const int* __restrict__ ids,
                           ushort* __restrict__ ent_emb, int* __restrict__ counts) {
    int e = blockIdx.x, b = blockIdx.y;
    __shared__ int sid[cM];
    int tid = threadIdx.x;
    if (tid < cM) sid[tid] = ids[b * cM + tid];
    __syncthreads();
    int cnt = 0;
    for (int m = 0; m < cM; m++) cnt += (sid[m] == e) ? 1 : 0;
    if (blockIdx.z == 0 && tid == 0) counts[b * cE + e] = cnt;
    int h = blockIdx.z * 256 + tid;
    {
        float mx = -1e30f;
        for (int m = 0; m < cM; m++)
            if (sid[m] == e) mx = fmaxf(mx, ent_lhs[(size_t)(b * cM + m) * cH + h]);
        float s = 0.f;
        for (int m = 0; m < cM; m++)
            if (sid[m] == e) s += __expf(ent_lhs[(size_t)(b * cM + m) * cH + h] - mx);
        ent_emb[(size_t)(b * cE + e) * cH + h] = f2bf((cnt > 0) ? (mx + __logf(s)) : 0.f);
    }
}

// ---------------------------------------------------------------------------
// Kernel 2: ent_attn[b][e][a][l] (bf16) = segment-mean of attn
__global__ void ent_attn_k(const float* __restrict__ attn, const int* __restrict__ ids,
                           const int* __restrict__ counts, ushort* __restrict__ ent_attn) {
    int ba = blockIdx.x;
    int b = ba / cA, a = ba % cA;
    int tid = threadIdx.x;
    int l = blockIdx.y * 256 + tid;
    __shared__ int sid[cM];
    __shared__ int scnt[cE];
    __shared__ float sacc[256 * 33];
    if (tid < cM) sid[tid] = ids[b * cM + tid];
    if (tid < cE) scnt[tid] = counts[b * cE + tid];
    float* acc = &sacc[tid * 33];
    for (int e2 = 0; e2 < cE; e2++) acc[e2] = 0.f;
    __syncthreads();
    const float* ap = attn + ((size_t)(b * cA + a) * cM) * cL + l;
    for (int m = 0; m < cM; m++) acc[sid[m]] += ap[(size_t)m * cL];
    for (int e2 = 0; e2 < cE; e2++) {
        ent_attn[((size_t)(b * cE + e2) * cA + a) * cL + l] =
            f2bf(acc[e2] / (float)max(scnt[e2], 1));
    }
}

// ---------------------------------------------------------------------------
// Kernel 3: w[b][r][l] = mean_a ha*ta, normalized over l (ushort4 vectorized)
__global__ void w_k(const ushort* __restrict__ ent_attn, const int* __restrict__ hts,
                    ushort* __restrict__ w) {
    int nr = blockIdx.x;
    int b = nr / cR;
    int he = hts[nr * 2 + 0], te = hts[nr * 2 + 1];
    int tid = threadIdx.x;
    int l0 = tid * 4;
    const ushort* ha = ent_attn + ((size_t)(b * cE + he) * cA) * cL + l0;
    const ushort* ta = ent_attn + ((size_t)(b * cE + te) * cA) * cL + l0;
    float v[4] = {0.f, 0.f, 0.f, 0.f};
#pragma unroll
    for (int a = 0; a < cA; a++) {
        ushort4v hv = *(const ushort4v*)&ha[(size_t)a * cL];
        ushort4v tv = *(const ushort4v*)&ta[(size_t)a * cL];
#pragma unroll
        for (int i = 0; i < 4; i++) v[i] += bf2f(hv[i]) * bf2f(tv[i]);
    }
    float psum = 0.f;
#pragma unroll
    for (int i = 0; i < 4; i++) { v[i] *= (1.0f / cA); psum += v[i]; }
    for (int off = 32; off > 0; off >>= 1) psum += __shfl_down(psum, off, 64);
    __shared__ float red[4];
    if ((tid & 63) == 0) red[tid >> 6] = psum;
    __syncthreads();
    float tot = red[0] + red[1] + red[2] + red[3];
    float inv = 1.0f / (tot + 1e-5f);
    ushort4v o;
#pragma unroll
    for (int i = 0; i < 4; i++) o[i] = f2bf(v[i] * inv);
    *(ushort4v*)&w[(size_t)nr * cL + l0] = o;
}

// ---------------------------------------------------------------------------
// Kernel 4: rel MFMA GEMM: rel[n][h] = sum_l w[n][l] * seqT[b][h][l]
__global__ __launch_bounds__(256) void
rel_mfma_k(const ushort* __restrict__ wbf, const ushort* __restrict__ seqT,
           ushort* __restrict__ relbf) {
    const int b = blockIdx.z;
    const int r0 = blockIdx.x * 128, h0 = blockIdx.y * 64;
    const int tid = threadIdx.x, lane = tid & 63, wv = tid >> 6;
    const int col = lane & 15, g = lane >> 4;

    __shared__ ushort sA[128 * 72];
    __shared__ ushort sB[64 * 72];

    float4v acc[2][4];
#pragma unroll
    for (int mt = 0; mt < 2; mt++)
#pragma unroll
        for (int ct = 0; ct < 4; ct++) acc[mt][ct] = (float4v){0.f, 0.f, 0.f, 0.f};

    for (int kt = 0; kt < cL; kt += 64) {
#pragma unroll
        for (int p = 0; p < 4; p++) {
            int t = tid + p * 256;
            int row = t >> 3, seg = t & 7;
            int r = min(r0 + row, cR - 1);
            *(short8*)&sA[row * 72 + seg * 8] =
                *(const short8*)&wbf[((size_t)b * cR + r) * cL + kt + seg * 8];
        }
#pragma unroll
        for (int p = 0; p < 2; p++) {
            int t = tid + p * 256;
            int c = t >> 3, seg = t & 7;
            *(short8*)&sB[c * 72 + seg * 8] =
                *(const short8*)&seqT[((size_t)b * cH + h0 + c) * cL + kt + seg * 8];
        }
        __syncthreads();
        const int wrow = wv * 32;
#pragma unroll
        for (int k0 = 0; k0 < 64; k0 += 32) {
            short8 a0 = *(const short8*)&sA[(wrow + col) * 72 + k0 + g * 8];
            short8 a1 = *(const short8*)&sA[(wrow + 16 + col) * 72 + k0 + g * 8];
#pragma unroll
            for (int ct = 0; ct < 4; ct++) {
                short8 bf = *(const short8*)&sB[(ct * 16 + col) * 72 + k0 + g * 8];
                acc[0][ct] = __builtin_amdgcn_mfma_f32_16x16x32_bf16(a0, bf, acc[0][ct], 0, 0, 0);
                acc[1][ct] = __builtin_amdgcn_mfma_f32_16x16x32_bf16(a1, bf, acc[1][ct], 0, 0, 0);
            }
        }
        __syncthreads();
    }
#pragma unroll
    for (int mt = 0; mt < 2; mt++) {
#pragma unroll
        for (int ct = 0; ct < 4; ct++) {
            int h = h0 + ct * 16 + col;
            int rowb = r0 + wv * 32 + mt * 16 + g * 4;
#pragma unroll
            for (int reg = 0; reg < 4; reg++) {
                int r = rowb + reg;
                if (r < cR)
                    relbf[((size_t)b * cR + r) * cH + h] = f2bf(acc[mt][ct][reg]);
            }
        }
    }
}

// ---------------------------------------------------------------------------
// Kernel 5: projection MFMA GEMM, head+tail fused (blockIdx.z = sel).
__global__ __launch_bounds__(256) void
proj_mfma_k(const ushort* __restrict__ ent_bf, const ushort* __restrict__ relbf,
            const int* __restrict__ hts,
            const ushort* __restrict__ WTh, const ushort* __restrict__ WTt,
            const float* __restrict__ head_b, const float* __restrict__ tail_b,
            ushort* __restrict__ hsp, ushort* __restrict__ tsp) {
    const int sel = blockIdx.z;
    const ushort* WTp = sel ? WTt : WTh;
    const float* bias = sel ? tail_b : head_b;
    ushort* outp = sel ? tsp : hsp;

    const int n0 = blockIdx.x * 64, e0 = blockIdx.y * 64;
    const int tid = threadIdx.x, lane = tid & 63, wv = tid >> 6;
    const int col = lane & 15, g = lane >> 4;

    __shared__ int sbase[64];
    __shared__ ushort sA[64 * 72];
    __shared__ ushort sB[64 * 72];

    if (tid < 64) {
        int n = n0 + tid, bb = n / cR;
        sbase[tid] = (bb * cE + hts[n * 2 + sel]) * cH;
    }
    __syncthreads();

    float4v acc[4];
#pragma unroll
    for (int ct = 0; ct < 4; ct++) acc[ct] = (float4v){0.f, 0.f, 0.f, 0.f};

    for (int kt = 0; kt < 2 * cH; kt += 64) {
        const bool first = kt < cH;
#pragma unroll
        for (int p = 0; p < 2; p++) {
            int t = tid + p * 256;
            int row = t >> 3, seg = t & 7;
            const ushort* src = first
                ? &ent_bf[(size_t)sbase[row] + kt + seg * 8]
                : &relbf[(size_t)(n0 + row) * cH + (kt - cH) + seg * 8];
            *(short8*)&sA[row * 72 + seg * 8] = *(const short8*)src;
        }
#pragma unroll
        for (int p = 0; p < 2; p++) {
            int t = tid + p * 256;
            int c = t >> 3, seg = t & 7;
            *(short8*)&sB[c * 72 + seg * 8] =
                *(const short8*)&WTp[(size_t)(e0 + c) * (2 * cH) + kt + seg * 8];
        }
        __syncthreads();
        const int wrow = wv * 16;
#pragma unroll
        for (int k0 = 0; k0 < 64; k0 += 32) {
            short8 a0 = *(const short8*)&sA[(wrow + col) * 72 + k0 + g * 8];
#pragma unroll
            for (int ct = 0; ct < 4; ct++) {
                short8 bf = *(const short8*)&sB[(ct * 16 + col) * 72 + k0 + g * 8];
                acc[ct] = __builtin_amdgcn_mfma_f32_16x16x32_bf16(a0, bf, acc[ct], 0, 0, 0);
            }
        }
        __syncthreads();
    }
#pragma unroll
    for (int ct = 0; ct < 4; ct++) {
        int e = e0 + ct * 16 + col;
        float bv = bias[e];
        int rowb = n0 + wv * 16 + g * 4;
#pragma unroll
        for (int reg = 0; reg < 4; reg++)
            outp[(size_t)(rowb + reg) * cEMB + e] = f2bf(tanhf(acc[ct][reg] + bv));
    }
}

// ---------------------------------------------------------------------------
// async stage of one Wf i-block (16 KB, frag-major linear) into LDS.
// wave wv copies bytes [wv*4096 + p*1024, +1KB); HW adds lane*16 on the LDS
// side, the global source carries the matching lane*16 (lane*8 ushorts).
static __device__ inline void stage_wf(const ushort* __restrict__ WfS, int i,
                                       ushort* dstbase, int wv, int lane) {
#pragma unroll
    for (int p = 0; p < 4; p++) {
        const ushort* src = WfS + (size_t)i * 8192 + wv * 2048 + p * 512 + lane * 8;
        ushort* dst = dstbase + wv * 2048 + p * 512;
        __builtin_amdgcn_global_load_lds(
            (const __attribute__((address_space(1))) unsigned int*)src,
            (__attribute__((address_space(3))) unsigned int*)dst, 16, 0, 0);
    }
}

// ---------------------------------------------------------------------------
// Kernel 6: bilinear v9 — ATOMIC-FREE.
// Post-mortem of v7/v8: two different W-delivery structures gave identical
// 125 µs with MfmaUtil/VALUBusy both <20% — the common, occupancy-invariant
// cost is the epilogue: ~9.2M f32 atomicAdds onto a 1.5 MB out region
// (WRITE_SIZE showed 35x write amplification: 54 MB for a 1.5 MB buffer).
// Same-cache-line RMW serialization at TCC is ~60-120 µs of work.
// v9: islices regrouped 8 groups x 3 islices -> grid (8, 31) = 248 blocks
// (~1/CU). Each block accumulates 3 islices (96 K-steps, W LDS-dbuf as v8)
// in registers and writes plain coalesced f32 partials part[grp][n][c]
// (c padded to 128). bil_reduce_k sums 8 partials + bias -> out.
// Partials (16.25 MB) live in the stream-dead ent_attn/wbuf/relbf region.
__global__ __launch_bounds__(256) void
bil_mfma9_k(const ushort* __restrict__ hsp, const ushort* __restrict__ tsp,
            const ushort* __restrict__ Wf, float* __restrict__ part) {
    const int grp = blockIdx.x;          // 0..7 -> islices 3g..3g+2
    const int n0 = blockIdx.y * 128;
    const int tid = threadIdx.x;
    const int lane = tid & 63, wv = tid >> 6;
    const int col = lane & 15, g4 = lane >> 4;
    const int rh = wv >> 1, cth = wv & 1;

    __shared__ float sHs[32 * 132];      // [i][row] for current islice
    __shared__ ushort sW[2][8192];       // double-buffered Wf i-block (16 KB)

    float4v acc[4][4];
#pragma unroll
    for (int mt = 0; mt < 4; mt++)
#pragma unroll
        for (int ct = 0; ct < 4; ct++) acc[mt][ct] = (float4v){0.f, 0.f, 0.f, 0.f};

    // 96 consecutive 16KB W-blocks for this group
    const ushort* WfG = Wf + (size_t)grp * 3 * 32 * 8192;

    stage_wf(WfG, 0, &sW[0][0], wv, lane);   // t = 0

    for (int s = 0; s < 3; ++s) {
        const int islice = grp * 3 + s;
        const int kb = islice >> 1;

        // stage hs tile for this islice -> f32 LDS, transposed
        for (int idx = tid; idx < 512; idx += 256) {
            int row = idx & 127, seg = idx >> 7;
            short8 v = *(const short8*)
                &hsp[(size_t)(n0 + row) * cEMB + islice * 32 + seg * 8];
#pragma unroll
            for (int jj = 0; jj < 8; jj++)
                sHs[(seg * 8 + jj) * 132 + row] = bf2f((ushort)v[jj]);
        }

        // ts A-fragments for this islice (registers, live for 32 steps)
        short8 tsA[4][2];
#pragma unroll
        for (int mt = 0; mt < 4; mt++)
#pragma unroll
            for (int kh = 0; kh < 2; kh++)
                tsA[mt][kh] = *(const short8*)
                    &tsp[(size_t)(n0 + rh * 64 + mt * 16 + col) * cEMB
                         + kb * 64 + kh * 32 + g4 * 8];

        __syncthreads();  // sHs written; W buffer for first step landed

        for (int i = 0; i < 32; ++i) {
            const int t = s * 32 + i;
            if (t + 1 < 96) stage_wf(WfG, t + 1, &sW[(t + 1) & 1][0], wv, lane);
            const ushort* sWb = &sW[t & 1][0];

            short8 wfr[2][4];
#pragma unroll
            for (int kh = 0; kh < 2; kh++)
#pragma unroll
                for (int ctl = 0; ctl < 4; ctl++)
                    wfr[kh][ctl] = *(const short8*)
                        &sWb[((kh * 8 + cth * 4 + ctl) * 64 + lane) * 8];

            float4v hsv[4];
#pragma unroll
            for (int mt = 0; mt < 4; mt++)
                hsv[mt] = *(const float4v*)&sHs[i * 132 + rh * 64 + mt * 16 + g4 * 4];

#pragma unroll
            for (int ctl = 0; ctl < 4; ctl++) {
#pragma unroll
                for (int mt = 0; mt < 4; mt++) {
                    float4v P = (float4v){0.f, 0.f, 0.f, 0.f};
                    P = __builtin_amdgcn_mfma_f32_16x16x32_bf16(tsA[mt][0], wfr[0][ctl], P, 0, 0, 0);
                    P = __builtin_amdgcn_mfma_f32_16x16x32_bf16(tsA[mt][1], wfr[1][ctl], P, 0, 0, 0);
                    acc[mt][ctl] += hsv[mt] * P;
                }
            }
            __syncthreads();  // readers done with sW[t&1]; sW[(t+1)&1] landed
        }
    }

    // epilogue: plain coalesced f32 stores (c padded to 128; c>=97 is junk
    // the reduce kernel never reads)
    float* pbase = part + (size_t)grp * cN * 128;
#pragma unroll
    for (int mt = 0; mt < 4; mt++) {
#pragma unroll
        for (int ctl = 0; ctl < 4; ctl++) {
            int c = (cth * 4 + ctl) * 16 + col;
            int rowb = n0 + rh * 64 + mt * 16 + g4 * 4;
#pragma unroll
            for (int reg = 0; reg < 4; reg++)
                pbase[(size_t)(rowb + reg) * 128 + c] = acc[mt][ctl][reg];
        }
    }
}

// ---------------------------------------------------------------------------
// Kernel 7: reduce 8 partials + bias -> out (replaces out_init + atomics)
__global__ void bil_reduce_k(const float* __restrict__ part,
                             const float* __restrict__ bil_b,
                             float* __restrict__ out) {
    int n = blockIdx.x;
    int c = threadIdx.x;            // 128 threads, c >= cC inactive
    if (c >= cC) return;
    float s = bil_b[c];
#pragma unroll
    for (int g = 0; g < cNG; g++)
        s += part[((size_t)g * cN + n) * 128 + c];
    out[(size_t)n * cC + c] = s;
}

// ---------------------------------------------------------------------------
extern "C" void kernel_launch(void* const* d_in, const int* in_sizes, int n_in,
                              void* d_out, int out_size, void* d_ws, size_t ws_size,
                              hipStream_t stream) {
    const float* seq_lhs  = (const float*)d_in[0];
    const float* ent_lhs  = (const float*)d_in[1];
    const float* attn     = (const float*)d_in[2];
    const int*   ids      = (const int*)d_in[3];
    const int*   hts      = (const int*)d_in[4];
    const float* head_W   = (const float*)d_in[5];
    const float* head_b   = (const float*)d_in[6];
    const float* tail_W   = (const float*)d_in[7];
    const float* tail_b   = (const float*)d_in[8];
    const float* bil_W    = (const float*)d_in[9];
    const float* bil_b    = (const float*)d_in[10];
    float* out = (float*)d_out;

    // workspace layout (byte offsets, 256B-aligned)
    char* ws = (char*)d_ws;
    int*    counts   = (int*)(ws + 0);             // 512 B
    ushort* ent_bf   = (ushort*)(ws + 512);        // 262144 B
    ushort* ent_attn = (ushort*)(ws + 262656);     // bf16, 4194304 B
    ushort* wbuf     = (ushort*)(ws + 4456960);    // 8126464 B
    ushort* relbf    = (ushort*)(ws + 12583424);   // 8126464 B
    ushort* hsp      = (ushort*)(ws + 20709888);   // 6094848 B
    ushort* tsp      = (ushort*)(ws + 26804736);   // 6094848 B
    ushort* Wf       = (ushort*)(ws + 32899584);   // 12582912 B
    ushort* WTh      = (ushort*)(ws + 45482496);   // 3145728 B
    ushort* WTt      = (ushort*)(ws + 48628224);   // 3145728 B
    ushort* seqT     = (ushort*)(ws + 51773952);   // 8388608 B  (end 60162560)
    // bilinear partials: 8 x 3968 x 128 x f32 = 16252928 B, overlaid on the
    // stream-dead ent_attn/wbuf/relbf region (all consumed before bil launch)
    float*  part     = (float*)(ws + 262656);

    hipLaunchKernelGGL(wf_build_k, dim3(768), dim3(256), 0, stream, bil_W, Wf);
    hipLaunchKernelGGL(tr_ht_k, dim3(64, 24, 2), dim3(256), 0, stream,
                       head_W, tail_W, WTh, WTt);
    hipLaunchKernelGGL(tr_bf16_k, dim3(32, 32, cB), dim3(256), 0, stream,
                       seq_lhs, seqT, cL, cH, cH);

    hipLaunchKernelGGL(ent_pool_k, dim3(cE, cB, 4), dim3(256), 0, stream,
                       ent_lhs, ids, ent_bf, counts);
    hipLaunchKernelGGL(ent_attn_k, dim3(cB * cA, cL / 256), dim3(256), 0, stream,
                       attn, ids, counts, ent_attn);
    hipLaunchKernelGGL(w_k, dim3(cN), dim3(256), 0, stream,
                       ent_attn, hts, wbuf);
    hipLaunchKernelGGL(rel_mfma_k, dim3(8, 16, cB), dim3(256), 0, stream,
                       wbuf, seqT, relbf);
    hipLaunchKernelGGL(proj_mfma_k, dim3(cN / 64, cEMB / 64, 2), dim3(256), 0, stream,
                       ent_bf, relbf, hts, WTh, WTt, head_b, tail_b, hsp, tsp);
    hipLaunchKernelGGL(bil_mfma9_k, dim3(cNG, cN / 128), dim3(256), 0, stream,
                       hsp, tsp, Wf, part);
    hipLaunchKernelGGL(bil_reduce_k, dim3(cN), dim3(128), 0, stream,
                       part, bil_b, out);
}

// Round 3
// 400.971 us; speedup vs baseline: 1.0468x; 1.0114x over previous
//
#include <hip/hip_runtime.h>
#include <hip/hip_bf16.h>
#include <math.h>

// Problem constants
constexpr int cB   = 4;
constexpr int cL   = 1024;
constexpr int cH   = 1024;
constexpr int cA   = 16;
constexpr int cM   = 128;
constexpr int cE   = 32;
constexpr int cR   = 992;
constexpr int cEMB = 768;
constexpr int cC   = 97;
constexpr int cN   = cB * cR;   // 3968
constexpr int cNG  = 8;         // islice groups (3 islices each)

typedef unsigned short ushort;
typedef __attribute__((ext_vector_type(4))) unsigned short ushort4v;
typedef __attribute__((ext_vector_type(8))) short short8;
typedef __attribute__((ext_vector_type(4))) float float4v;

static __device__ inline float bf2f(ushort u) {
    unsigned v = ((unsigned)u) << 16;
    float f;
    __builtin_memcpy(&f, &v, 4);
    return f;
}
static __device__ inline ushort f2bf(float f) {
    unsigned u;
    __builtin_memcpy(&u, &f, 4);
    unsigned r = (u + 0x7FFFu + ((u >> 16) & 1u)) >> 16;
    return (ushort)r;
}

// ---------------------------------------------------------------------------
// Generic transpose f32 -> bf16: src[z][R][C] -> dst[z][Cp][R], zero-pad c>=C
__global__ void tr_bf16_k(const float* __restrict__ src, ushort* __restrict__ dst,
                          int R, int C, int Cp) {
    int z = blockIdx.z;
    int r0 = blockIdx.x * 32, c0 = blockIdx.y * 32;
    int tx = threadIdx.x & 31, ty = threadIdx.x >> 5;  // ty 0..7
    __shared__ float tile[32][33];
    for (int p = 0; p < 4; p++) {
        int r = r0 + ty + p * 8, c = c0 + tx;
        tile[ty + p * 8][tx] = (r < R && c < C) ? src[((size_t)z * R + r) * C + c] : 0.f;
    }
    __syncthreads();
    for (int p = 0; p < 4; p++) {
        int c = c0 + ty + p * 8, r = r0 + tx;
        if (c < Cp && r < R)
            dst[((size_t)z * Cp + c) * R + r] = f2bf(tile[tx][ty + p * 8]);
    }
}

// Head+tail weight transpose in one launch (z selects which matrix)
__global__ void tr_ht_k(const float* __restrict__ Wh, const float* __restrict__ Wt,
                        ushort* __restrict__ WTh, ushort* __restrict__ WTt) {
    const float* src = blockIdx.z ? Wt : Wh;
    ushort* dst = blockIdx.z ? WTt : WTh;
    int r0 = blockIdx.x * 32, c0 = blockIdx.y * 32;
    int tx = threadIdx.x & 31, ty = threadIdx.x >> 5;
    __shared__ float tile[32][33];
    for (int p = 0; p < 4; p++) {
        int r = r0 + ty + p * 8, c = c0 + tx;
        tile[ty + p * 8][tx] = src[(size_t)r * cEMB + c];
    }
    __syncthreads();
    for (int p = 0; p < 4; p++) {
        int c = c0 + ty + p * 8, r = r0 + tx;
        dst[(size_t)c * (2 * cH) + r] = f2bf(tile[tx][ty + p * 8]);
    }
}

// ---------------------------------------------------------------------------
// Build fragment-ordered bilinear weights (16 frags per i, v3 layout):
// Wf[si][f][lane][8] bf16, f = khalf*8+ct,
// element = W[(si*64 + j)][c], j = khalf*32 + (lane>>4)*8 + jj, c = ct*16 + (lane&15)
__global__ void wf_build_k(const float* __restrict__ W, ushort* __restrict__ Wf) {
    const int si = blockIdx.x;
    const int tid = threadIdx.x;
    __shared__ ushort sWb[64 * 136];
    for (int idx = tid; idx < 64 * 128; idx += 256) {
        int r = idx >> 7, c = idx & 127;
        float v = (c < cC) ? W[((size_t)si * 64 + r) * cC + c] : 0.f;
        sWb[r * 136 + c] = f2bf(v);
    }
    __syncthreads();
#pragma unroll
    for (int p = 0; p < 4; p++) {
        int e = tid + p * 256;          // 0..1023
        int f = e >> 6, lane = e & 63;
        int g = lane >> 4, col = lane & 15;
        int khalf = f >> 3, ct = f & 7;
        int jb = khalf * 32 + g * 8;
        int c = ct * 16 + col;
        short8 v;
#pragma unroll
        for (int jj = 0; jj < 8; jj++) v[jj] = (short)sWb[(jb + jj) * 136 + c];
        *(short8*)&Wf[(((size_t)si * 16 + f) * 64 + lane) * 8] = v;
    }
}

// ---------------------------------------------------------------------------
// Kernel 1: per-(b,e) logsumexp pooling of ent_lhs; writes bf16.
__global__ void ent_pool_k(const float* __restrict__ ent_lhs, const int* __restrict__ ids,
                           ushort* __restrict__ ent_emb, int* __restrict__ counts) {
    int e = blockIdx.x, b = blockIdx.y;
    __shared__ int sid[cM];
    int tid = threadIdx.x;
    if (tid < cM) sid[tid] = ids[b * cM + tid];
    __syncthreads();
    int cnt = 0;
    for (int m = 0; m < cM; m++) cnt += (sid[m] == e) ? 1 : 0;
    if (blockIdx.z == 0 && tid == 0) counts[b * cE + e] = cnt;
    int h = blockIdx.z * 256 + tid;
    {
        float mx = -1e30f;
        for (int m = 0; m < cM; m++)
            if (sid[m] == e) mx = fmaxf(mx, ent_lhs[(size_t)(b * cM + m) * cH + h]);
        float s = 0.f;
        for (int m = 0; m < cM; m++)
            if (sid[m] == e) s += __expf(ent_lhs[(size_t)(b * cM + m) * cH + h] - mx);
        ent_emb[(size_t)(b * cE + e) * cH + h] = f2bf((cnt > 0) ? (mx + __logf(s)) : 0.f);
    }
}

// ---------------------------------------------------------------------------
// Kernel 2: ent_attn[b][e][a][l] (bf16) = segment-mean of attn
__global__ void ent_attn_k(const float* __restrict__ attn, const int* __restrict__ ids,
                           const int* __restrict__ counts, ushort* __restrict__ ent_attn) {
    int ba = blockIdx.x;
    int b = ba / cA, a = ba % cA;
    int tid = threadIdx.x;
    int l = blockIdx.y * 256 + tid;
    __shared__ int sid[cM];
    __shared__ int scnt[cE];
    __shared__ float sacc[256 * 33];
    if (tid < cM) sid[tid] = ids[b * cM + tid];
    if (tid < cE) scnt[tid] = counts[b * cE + tid];
    float* acc = &sacc[tid * 33];
    for (int e2 = 0; e2 < cE; e2++) acc[e2] = 0.f;
    __syncthreads();
    const float* ap = attn + ((size_t)(b * cA + a) * cM) * cL + l;
    for (int m = 0; m < cM; m++) acc[sid[m]] += ap[(size_t)m * cL];
    for (int e2 = 0; e2 < cE; e2++) {
        ent_attn[((size_t)(b * cE + e2) * cA + a) * cL + l] =
            f2bf(acc[e2] / (float)max(scnt[e2], 1));
    }
}

// ---------------------------------------------------------------------------
// Kernel 3: w[b][r][l] = mean_a ha*ta, normalized over l (ushort4 vectorized)
__global__ void w_k(const ushort* __restrict__ ent_attn, const int* __restrict__ hts,
                    ushort* __restrict__ w) {
    int nr = blockIdx.x;
    int b = nr / cR;
    int he = hts[nr * 2 + 0], te = hts[nr * 2 + 1];
    int tid = threadIdx.x;
    int l0 = tid * 4;
    const ushort* ha = ent_attn + ((size_t)(b * cE + he) * cA) * cL + l0;
    const ushort* ta = ent_attn + ((size_t)(b * cE + te) * cA) * cL + l0;
    float v[4] = {0.f, 0.f, 0.f, 0.f};
#pragma unroll
    for (int a = 0; a < cA; a++) {
        ushort4v hv = *(const ushort4v*)&ha[(size_t)a * cL];
        ushort4v tv = *(const ushort4v*)&ta[(size_t)a * cL];
#pragma unroll
        for (int i = 0; i < 4; i++) v[i] += bf2f(hv[i]) * bf2f(tv[i]);
    }
    float psum = 0.f;
#pragma unroll
    for (int i = 0; i < 4; i++) { v[i] *= (1.0f / cA); psum += v[i]; }
    for (int off = 32; off > 0; off >>= 1) psum += __shfl_down(psum, off, 64);
    __shared__ float red[4];
    if ((tid & 63) == 0) red[tid >> 6] = psum;
    __syncthreads();
    float tot = red[0] + red[1] + red[2] + red[3];
    float inv = 1.0f / (tot + 1e-5f);
    ushort4v o;
#pragma unroll
    for (int i = 0; i < 4; i++) o[i] = f2bf(v[i] * inv);
    *(ushort4v*)&w[(size_t)nr * cL + l0] = o;
}

// ---------------------------------------------------------------------------
// Kernel 4: rel MFMA GEMM: rel[n][h] = sum_l w[n][l] * seqT[b][h][l]
__global__ __launch_bounds__(256) void
rel_mfma_k(const ushort* __restrict__ wbf, const ushort* __restrict__ seqT,
           ushort* __restrict__ relbf) {
    const int b = blockIdx.z;
    const int r0 = blockIdx.x * 128, h0 = blockIdx.y * 64;
    const int tid = threadIdx.x, lane = tid & 63, wv = tid >> 6;
    const int col = lane & 15, g = lane >> 4;

    __shared__ ushort sA[128 * 72];
    __shared__ ushort sB[64 * 72];

    float4v acc[2][4];
#pragma unroll
    for (int mt = 0; mt < 2; mt++)
#pragma unroll
        for (int ct = 0; ct < 4; ct++) acc[mt][ct] = (float4v){0.f, 0.f, 0.f, 0.f};

    for (int kt = 0; kt < cL; kt += 64) {
#pragma unroll
        for (int p = 0; p < 4; p++) {
            int t = tid + p * 256;
            int row = t >> 3, seg = t & 7;
            int r = min(r0 + row, cR - 1);
            *(short8*)&sA[row * 72 + seg * 8] =
                *(const short8*)&wbf[((size_t)b * cR + r) * cL + kt + seg * 8];
        }
#pragma unroll
        for (int p = 0; p < 2; p++) {
            int t = tid + p * 256;
            int c = t >> 3, seg = t & 7;
            *(short8*)&sB[c * 72 + seg * 8] =
                *(const short8*)&seqT[((size_t)b * cH + h0 + c) * cL + kt + seg * 8];
        }
        __syncthreads();
        const int wrow = wv * 32;
#pragma unroll
        for (int k0 = 0; k0 < 64; k0 += 32) {
            short8 a0 = *(const short8*)&sA[(wrow + col) * 72 + k0 + g * 8];
            short8 a1 = *(const short8*)&sA[(wrow + 16 + col) * 72 + k0 + g * 8];
#pragma unroll
            for (int ct = 0; ct < 4; ct++) {
                short8 bf = *(const short8*)&sB[(ct * 16 + col) * 72 + k0 + g * 8];
                acc[0][ct] = __builtin_amdgcn_mfma_f32_16x16x32_bf16(a0, bf, acc[0][ct], 0, 0, 0);
                acc[1][ct] = __builtin_amdgcn_mfma_f32_16x16x32_bf16(a1, bf, acc[1][ct], 0, 0, 0);
            }
        }
        __syncthreads();
    }
#pragma unroll
    for (int mt = 0; mt < 2; mt++) {
#pragma unroll
        for (int ct = 0; ct < 4; ct++) {
            int h = h0 + ct * 16 + col;
            int rowb = r0 + wv * 32 + mt * 16 + g * 4;
#pragma unroll
            for (int reg = 0; reg < 4; reg++) {
                int r = rowb + reg;
                if (r < cR)
                    relbf[((size_t)b * cR + r) * cH + h] = f2bf(acc[mt][ct][reg]);
            }
        }
    }
}

// ---------------------------------------------------------------------------
// Kernel 5: projection MFMA GEMM, head+tail fused (blockIdx.z = sel).
__global__ __launch_bounds__(256) void
proj_mfma_k(const ushort* __restrict__ ent_bf, const ushort* __restrict__ relbf,
            const int* __restrict__ hts,
            const ushort* __restrict__ WTh, const ushort* __restrict__ WTt,
            const float* __restrict__ head_b, const float* __restrict__ tail_b,
            ushort* __restrict__ hsp, ushort* __restrict__ tsp) {
    const int sel = blockIdx.z;
    const ushort* WTp = sel ? WTt : WTh;
    const float* bias = sel ? tail_b : head_b;
    ushort* outp = sel ? tsp : hsp;

    const int n0 = blockIdx.x * 64, e0 = blockIdx.y * 64;
    const int tid = threadIdx.x, lane = tid & 63, wv = tid >> 6;
    const int col = lane & 15, g = lane >> 4;

    __shared__ int sbase[64];
    __shared__ ushort sA[64 * 72];
    __shared__ ushort sB[64 * 72];

    if (tid < 64) {
        int n = n0 + tid, bb = n / cR;
        sbase[tid] = (bb * cE + hts[n * 2 + sel]) * cH;
    }
    __syncthreads();

    float4v acc[4];
#pragma unroll
    for (int ct = 0; ct < 4; ct++) acc[ct] = (float4v){0.f, 0.f, 0.f, 0.f};

    for (int kt = 0; kt < 2 * cH; kt += 64) {
        const bool first = kt < cH;
#pragma unroll
        for (int p = 0; p < 2; p++) {
            int t = tid + p * 256;
            int row = t >> 3, seg = t & 7;
            const ushort* src = first
                ? &ent_bf[(size_t)sbase[row] + kt + seg * 8]
                : &relbf[(size_t)(n0 + row) * cH + (kt - cH) + seg * 8];
            *(short8*)&sA[row * 72 + seg * 8] = *(const short8*)src;
        }
#pragma unroll
        for (int p = 0; p < 2; p++) {
            int t = tid + p * 256;
            int c = t >> 3, seg = t & 7;
            *(short8*)&sB[c * 72 + seg * 8] =
                *(const short8*)&WTp[(size_t)(e0 + c) * (2 * cH) + kt + seg * 8];
        }
        __syncthreads();
        const int wrow = wv * 16;
#pragma unroll
        for (int k0 = 0; k0 < 64; k0 += 32) {
            short8 a0 = *(const short8*)&sA[(wrow + col) * 72 + k0 + g * 8];
#pragma unroll
            for (int ct = 0; ct < 4; ct++) {
                short8 bf = *(const short8*)&sB[(ct * 16 + col) * 72 + k0 + g * 8];
                acc[ct] = __builtin_amdgcn_mfma_f32_16x16x32_bf16(a0, bf, acc[ct], 0, 0, 0);
            }
        }
        __syncthreads();
    }
#pragma unroll
    for (int ct = 0; ct < 4; ct++) {
        int e = e0 + ct * 16 + col;
        float bv = bias[e];
        int rowb = n0 + wv * 16 + g * 4;
#pragma unroll
        for (int reg = 0; reg < 4; reg++)
            outp[(size_t)(rowb + reg) * cEMB + e] = f2bf(tanhf(acc[ct][reg] + bv));
    }
}

// ---------------------------------------------------------------------------
// async stage of one Wf i-block (16 KB, frag-major linear) into LDS.
// wave wv copies bytes [wv*4096 + p*1024, +1KB); HW adds lane*16 on the LDS
// side, the global source carries the matching lane*16 (lane*8 ushorts).
static __device__ inline void stage_wf(const ushort* __restrict__ WfS, int i,
                                       ushort* dstbase, int wv, int lane) {
#pragma unroll
    for (int p = 0; p < 4; p++) {
        const ushort* src = WfS + (size_t)i * 8192 + wv * 2048 + p * 512 + lane * 8;
        ushort* dst = dstbase + wv * 2048 + p * 512;
        __builtin_amdgcn_global_load_lds(
            (const __attribute__((address_space(1))) unsigned int*)src,
            (__attribute__((address_space(3))) unsigned int*)dst, 16, 0, 0);
    }
}

// ---------------------------------------------------------------------------
// Kernel 6: bilinear v10 — counted-vmcnt deep pipeline (T3+T4).
// Post-mortem v7/v8/v9: per-step CU-time constant ~2800 cyc across three
// W-delivery schemes; resource arithmetic (MFMA 160, VALU ~550, LDS ~600)
// accounts for <1/3. Common cause: depth-1 prefetch + per-step vmcnt(0)
// drain (__syncthreads) exposes L3-under-load latency (~2000+ cyc) of the
// Wf stream on EVERY step.
// v10: 6-deep LDS ring, depth-5 prefetch, raw s_barrier + counted
// s_waitcnt vmcnt(16) — 16 loads stay in flight across every barrier.
// Slot (t+5)%6 is the slot read at step t-1, certified free by the top
// barrier. Uniform (t+5)%96 wrap avoids tail-count branches (junk lands in
// never-again-read slots); vmcnt(0) drain after the loop so no DMA is in
// flight at workgroup teardown. Numerics identical to v9.
__global__ __launch_bounds__(256) void
bil_mfma10_k(const ushort* __restrict__ hsp, const ushort* __restrict__ tsp,
             const ushort* __restrict__ Wf, float* __restrict__ part) {
    const int grp = blockIdx.x;          // 0..7 -> islices 3g..3g+2
    const int n0 = blockIdx.y * 128;
    const int tid = threadIdx.x;
    const int lane = tid & 63, wv = tid >> 6;
    const int col = lane & 15, g4 = lane >> 4;
    const int rh = wv >> 1, cth = wv & 1;

    __shared__ float sHs[32 * 132];      // [i][row] for current islice
    __shared__ ushort sW[6][8192];       // 6-deep ring of Wf i-blocks (16 KB)

    float4v acc[4][4];
#pragma unroll
    for (int mt = 0; mt < 4; mt++)
#pragma unroll
        for (int ct = 0; ct < 4; ct++) acc[mt][ct] = (float4v){0.f, 0.f, 0.f, 0.f};

    // 96 consecutive 16KB W-blocks for this group
    const ushort* WfG = Wf + (size_t)grp * 3 * 32 * 8192;

    // prologue: depth-5 prefetch (20 loads/wave outstanding)
#pragma unroll
    for (int q = 0; q < 5; q++) stage_wf(WfG, q, &sW[q][0], wv, lane);

    for (int s = 0; s < 3; ++s) {
        const int islice = grp * 3 + s;
        const int kb = islice >> 1;

        // all waves done reading previous sHs (computed last step before here)
        __builtin_amdgcn_s_barrier();

        // stage hs tile for this islice -> f32 LDS, transposed
        for (int idx = tid; idx < 512; idx += 256) {
            int row = idx & 127, seg = idx >> 7;
            short8 v = *(const short8*)
                &hsp[(size_t)(n0 + row) * cEMB + islice * 32 + seg * 8];
#pragma unroll
            for (int jj = 0; jj < 8; jj++)
                sHs[(seg * 8 + jj) * 132 + row] = bf2f((ushort)v[jj]);
        }

        // ts A-fragments for this islice (registers, live for 32 steps)
        short8 tsA[4][2];
#pragma unroll
        for (int mt = 0; mt < 4; mt++)
#pragma unroll
            for (int kh = 0; kh < 2; kh++)
                tsA[mt][kh] = *(const short8*)
                    &tsp[(size_t)(n0 + rh * 64 + mt * 16 + col) * cEMB
                         + kb * 64 + kh * 32 + g4 * 8];

        // sHs writes visible to all waves (keep DMA prefetch in flight:
        // no vmcnt here — compiler-inserted waits cover the tsA loads)
        asm volatile("s_waitcnt lgkmcnt(0)" ::: "memory");
        __builtin_amdgcn_s_barrier();
        __builtin_amdgcn_sched_barrier(0);

        for (int i = 0; i < 32; ++i) {
            const int t = s * 32 + i;
            // wait for step t's 4 DMA loads (queue: t..t+4 = 20 outstanding)
            asm volatile("s_waitcnt vmcnt(16)" ::: "memory");
            __builtin_amdgcn_s_barrier();   // all quarters landed; slot
                                            // (t+5)%6 free (read at t-1)
            __builtin_amdgcn_sched_barrier(0);
            stage_wf(WfG, (t + 5) % 96, &sW[(t + 5) % 6][0], wv, lane);

            const ushort* sWb = &sW[t % 6][0];

            short8 wfr[2][4];
#pragma unroll
            for (int kh = 0; kh < 2; kh++)
#pragma unroll
                for (int ctl = 0; ctl < 4; ctl++)
                    wfr[kh][ctl] = *(const short8*)
                        &sWb[((kh * 8 + cth * 4 + ctl) * 64 + lane) * 8];

            float4v hsv[4];
#pragma unroll
            for (int mt = 0; mt < 4; mt++)
                hsv[mt] = *(const float4v*)&sHs[i * 132 + rh * 64 + mt * 16 + g4 * 4];

#pragma unroll
            for (int ctl = 0; ctl < 4; ctl++) {
#pragma unroll
                for (int mt = 0; mt < 4; mt++) {
                    float4v P = (float4v){0.f, 0.f, 0.f, 0.f};
                    P = __builtin_amdgcn_mfma_f32_16x16x32_bf16(tsA[mt][0], wfr[0][ctl], P, 0, 0, 0);
                    P = __builtin_amdgcn_mfma_f32_16x16x32_bf16(tsA[mt][1], wfr[1][ctl], P, 0, 0, 0);
                    acc[mt][ctl] += hsv[mt] * P;
                }
            }
            // no bottom barrier: next step's top barrier protects slot reuse
        }
    }

    // drain in-flight (junk) DMAs before workgroup teardown
    asm volatile("s_waitcnt vmcnt(0)" ::: "memory");

    // epilogue: plain coalesced f32 stores (c padded to 128; c>=97 is junk
    // the reduce kernel never reads)
    float* pbase = part + (size_t)grp * cN * 128;
#pragma unroll
    for (int mt = 0; mt < 4; mt++) {
#pragma unroll
        for (int ctl = 0; ctl < 4; ctl++) {
            int c = (cth * 4 + ctl) * 16 + col;
            int rowb = n0 + rh * 64 + mt * 16 + g4 * 4;
#pragma unroll
            for (int reg = 0; reg < 4; reg++)
                pbase[(size_t)(rowb + reg) * 128 + c] = acc[mt][ctl][reg];
        }
    }
}

// ---------------------------------------------------------------------------
// Kernel 7: reduce 8 partials + bias -> out (replaces out_init + atomics)
__global__ void bil_reduce_k(const float* __restrict__ part,
                             const float* __restrict__ bil_b,
                             float* __restrict__ out) {
    int n = blockIdx.x;
    int c = threadIdx.x;            // 128 threads, c >= cC inactive
    if (c >= cC) return;
    float s = bil_b[c];
#pragma unroll
    for (int g = 0; g < cNG; g++)
        s += part[((size_t)g * cN + n) * 128 + c];
    out[(size_t)n * cC + c] = s;
}

// ---------------------------------------------------------------------------
extern "C" void kernel_launch(void* const* d_in, const int* in_sizes, int n_in,
                              void* d_out, int out_size, void* d_ws, size_t ws_size,
                              hipStream_t stream) {
    const float* seq_lhs  = (const float*)d_in[0];
    const float* ent_lhs  = (const float*)d_in[1];
    const float* attn     = (const float*)d_in[2];
    const int*   ids      = (const int*)d_in[3];
    const int*   hts      = (const int*)d_in[4];
    const float* head_W   = (const float*)d_in[5];
    const float* head_b   = (const float*)d_in[6];
    const float* tail_W   = (const float*)d_in[7];
    const float* tail_b   = (const float*)d_in[8];
    const float* bil_W    = (const float*)d_in[9];
    const float* bil_b    = (const float*)d_in[10];
    float* out = (float*)d_out;

    // workspace layout (byte offsets, 256B-aligned)
    char* ws = (char*)d_ws;
    int*    counts   = (int*)(ws + 0);             // 512 B
    ushort* ent_bf   = (ushort*)(ws + 512);        // 262144 B
    ushort* ent_attn = (ushort*)(ws + 262656);     // bf16, 4194304 B
    ushort* wbuf     = (ushort*)(ws + 4456960);    // 8126464 B
    ushort* relbf    = (ushort*)(ws + 12583424);   // 8126464 B
    ushort* hsp      = (ushort*)(ws + 20709888);   // 6094848 B
    ushort* tsp      = (ushort*)(ws + 26804736);   // 6094848 B
    ushort* Wf       = (ushort*)(ws + 32899584);   // 12582912 B
    ushort* WTh      = (ushort*)(ws + 45482496);   // 3145728 B
    ushort* WTt      = (ushort*)(ws + 48628224);   // 3145728 B
    ushort* seqT     = (ushort*)(ws + 51773952);   // 8388608 B  (end 60162560)
    // bilinear partials: 8 x 3968 x 128 x f32 = 16252928 B, overlaid on the
    // stream-dead ent_attn/wbuf/relbf region (all consumed before bil launch)
    float*  part     = (float*)(ws + 262656);

    hipLaunchKernelGGL(wf_build_k, dim3(768), dim3(256), 0, stream, bil_W, Wf);
    hipLaunchKernelGGL(tr_ht_k, dim3(64, 24, 2), dim3(256), 0, stream,
                       head_W, tail_W, WTh, WTt);
    hipLaunchKernelGGL(tr_bf16_k, dim3(32, 32, cB), dim3(256), 0, stream,
                       seq_lhs, seqT, cL, cH, cH);

    hipLaunchKernelGGL(ent_pool_k, dim3(cE, cB, 4), dim3(256), 0, stream,
                       ent_lhs, ids, ent_bf, counts);
    hipLaunchKernelGGL(ent_attn_k, dim3(cB * cA, cL / 256), dim3(256), 0, stream,
                       attn, ids, counts, ent_attn);
    hipLaunchKernelGGL(w_k, dim3(cN), dim3(256), 0, stream,
                       ent_attn, hts, wbuf);
    hipLaunchKernelGGL(rel_mfma_k, dim3(8, 16, cB), dim3(256), 0, stream,
                       wbuf, seqT, relbf);
    hipLaunchKernelGGL(proj_mfma_k, dim3(cN / 64, cEMB / 64, 2), dim3(256), 0, stream,
                       ent_bf, relbf, hts, WTh, WTt, head_b, tail_b, hsp, tsp);
    hipLaunchKernelGGL(bil_mfma10_k, dim3(cNG, cN / 128), dim3(256), 0, stream,
                       hsp, tsp, Wf, part);
    hipLaunchKernelGGL(bil_reduce_k, dim3(cN), dim3(128), 0, stream,
                       part, bil_b, out);
}

// Round 4
// 347.628 us; speedup vs baseline: 1.2075x; 1.1534x over previous
//
#include <hip/hip_runtime.h>
#include <hip/hip_bf16.h>
#include <math.h>

// Problem constants
constexpr int cB   = 4;
constexpr int cL   = 1024;
constexpr int cH   = 1024;
constexpr int cA   = 16;
constexpr int cM   = 128;
constexpr int cE   = 32;
constexpr int cR   = 992;
constexpr int cEMB = 768;
constexpr int cC   = 97;
constexpr int cN   = cB * cR;   // 3968
constexpr int cNG  = 8;         // islice groups (3 islices each)

typedef unsigned short ushort;
typedef __attribute__((ext_vector_type(4))) unsigned short ushort4v;
typedef __attribute__((ext_vector_type(8))) short short8;
typedef __attribute__((ext_vector_type(4))) float float4v;

static __device__ inline float bf2f(ushort u) {
    unsigned v = ((unsigned)u) << 16;
    float f;
    __builtin_memcpy(&f, &v, 4);
    return f;
}
static __device__ inline ushort f2bf(float f) {
    unsigned u;
    __builtin_memcpy(&u, &f, 4);
    unsigned r = (u + 0x7FFFu + ((u >> 16) & 1u)) >> 16;
    return (ushort)r;
}

// ---------------------------------------------------------------------------
// Generic transpose f32 -> bf16: src[z][R][C] -> dst[z][Cp][R], zero-pad c>=C
__global__ void tr_bf16_k(const float* __restrict__ src, ushort* __restrict__ dst,
                          int R, int C, int Cp) {
    int z = blockIdx.z;
    int r0 = blockIdx.x * 32, c0 = blockIdx.y * 32;
    int tx = threadIdx.x & 31, ty = threadIdx.x >> 5;  // ty 0..7
    __shared__ float tile[32][33];
    for (int p = 0; p < 4; p++) {
        int r = r0 + ty + p * 8, c = c0 + tx;
        tile[ty + p * 8][tx] = (r < R && c < C) ? src[((size_t)z * R + r) * C + c] : 0.f;
    }
    __syncthreads();
    for (int p = 0; p < 4; p++) {
        int c = c0 + ty + p * 8, r = r0 + tx;
        if (c < Cp && r < R)
            dst[((size_t)z * Cp + c) * R + r] = f2bf(tile[tx][ty + p * 8]);
    }
}

// Head+tail weight transpose in one launch (z selects which matrix)
__global__ void tr_ht_k(const float* __restrict__ Wh, const float* __restrict__ Wt,
                        ushort* __restrict__ WTh, ushort* __restrict__ WTt) {
    const float* src = blockIdx.z ? Wt : Wh;
    ushort* dst = blockIdx.z ? WTt : WTh;
    int r0 = blockIdx.x * 32, c0 = blockIdx.y * 32;
    int tx = threadIdx.x & 31, ty = threadIdx.x >> 5;
    __shared__ float tile[32][33];
    for (int p = 0; p < 4; p++) {
        int r = r0 + ty + p * 8, c = c0 + tx;
        tile[ty + p * 8][tx] = src[(size_t)r * cEMB + c];
    }
    __syncthreads();
    for (int p = 0; p < 4; p++) {
        int c = c0 + ty + p * 8, r = r0 + tx;
        dst[(size_t)c * (2 * cH) + r] = f2bf(tile[tx][ty + p * 8]);
    }
}

// ---------------------------------------------------------------------------
// Build fragment-ordered bilinear weights (16 frags per i, v3 layout):
// Wf[si][f][lane][8] bf16, f = khalf*8+ct,
// element = W[(si*64 + j)][c], j = khalf*32 + (lane>>4)*8 + jj, c = ct*16 + (lane&15)
__global__ void wf_build_k(const float* __restrict__ W, ushort* __restrict__ Wf) {
    const int si = blockIdx.x;
    const int tid = threadIdx.x;
    __shared__ ushort sWb[64 * 136];
    for (int idx = tid; idx < 64 * 128; idx += 256) {
        int r = idx >> 7, c = idx & 127;
        float v = (c < cC) ? W[((size_t)si * 64 + r) * cC + c] : 0.f;
        sWb[r * 136 + c] = f2bf(v);
    }
    __syncthreads();
#pragma unroll
    for (int p = 0; p < 4; p++) {
        int e = tid + p * 256;          // 0..1023
        int f = e >> 6, lane = e & 63;
        int g = lane >> 4, col = lane & 15;
        int khalf = f >> 3, ct = f & 7;
        int jb = khalf * 32 + g * 8;
        int c = ct * 16 + col;
        short8 v;
#pragma unroll
        for (int jj = 0; jj < 8; jj++) v[jj] = (short)sWb[(jb + jj) * 136 + c];
        *(short8*)&Wf[(((size_t)si * 16 + f) * 64 + lane) * 8] = v;
    }
}

// ---------------------------------------------------------------------------
// Kernel 1: per-(b,e) logsumexp pooling of ent_lhs; writes bf16.
__global__ void ent_pool_k(const float* __restrict__ ent_lhs, const int* __restrict__ ids,
                           ushort* __restrict__ ent_emb, int* __restrict__ counts) {
    int e = blockIdx.x, b = blockIdx.y;
    __shared__ int sid[cM];
    int tid = threadIdx.x;
    if (tid < cM) sid[tid] = ids[b * cM + tid];
    __syncthreads();
    int cnt = 0;
    for (int m = 0; m < cM; m++) cnt += (sid[m] == e) ? 1 : 0;
    if (blockIdx.z == 0 && tid == 0) counts[b * cE + e] = cnt;
    int h = blockIdx.z * 256 + tid;
    {
        float mx = -1e30f;
        for (int m = 0; m < cM; m++)
            if (sid[m] == e) mx = fmaxf(mx, ent_lhs[(size_t)(b * cM + m) * cH + h]);
        float s = 0.f;
        for (int m = 0; m < cM; m++)
            if (sid[m] == e) s += __expf(ent_lhs[(size_t)(b * cM + m) * cH + h] - mx);
        ent_emb[(size_t)(b * cE + e) * cH + h] = f2bf((cnt > 0) ? (mx + __logf(s)) : 0.f);
    }
}

// ---------------------------------------------------------------------------
// Kernel 2: ent_attn[b][e][a][l] (bf16) = segment-mean of attn
__global__ void ent_attn_k(const float* __restrict__ attn, const int* __restrict__ ids,
                           const int* __restrict__ counts, ushort* __restrict__ ent_attn) {
    int ba = blockIdx.x;
    int b = ba / cA, a = ba % cA;
    int tid = threadIdx.x;
    int l = blockIdx.y * 256 + tid;
    __shared__ int sid[cM];
    __shared__ int scnt[cE];
    __shared__ float sacc[256 * 33];
    if (tid < cM) sid[tid] = ids[b * cM + tid];
    if (tid < cE) scnt[tid] = counts[b * cE + tid];
    float* acc = &sacc[tid * 33];
    for (int e2 = 0; e2 < cE; e2++) acc[e2] = 0.f;
    __syncthreads();
    const float* ap = attn + ((size_t)(b * cA + a) * cM) * cL + l;
    for (int m = 0; m < cM; m++) acc[sid[m]] += ap[(size_t)m * cL];
    for (int e2 = 0; e2 < cE; e2++) {
        ent_attn[((size_t)(b * cE + e2) * cA + a) * cL + l] =
            f2bf(acc[e2] / (float)max(scnt[e2], 1));
    }
}

// ---------------------------------------------------------------------------
// Kernel 3: w[b][r][l] = mean_a ha*ta, normalized over l (ushort4 vectorized)
__global__ void w_k(const ushort* __restrict__ ent_attn, const int* __restrict__ hts,
                    ushort* __restrict__ w) {
    int nr = blockIdx.x;
    int b = nr / cR;
    int he = hts[nr * 2 + 0], te = hts[nr * 2 + 1];
    int tid = threadIdx.x;
    int l0 = tid * 4;
    const ushort* ha = ent_attn + ((size_t)(b * cE + he) * cA) * cL + l0;
    const ushort* ta = ent_attn + ((size_t)(b * cE + te) * cA) * cL + l0;
    float v[4] = {0.f, 0.f, 0.f, 0.f};
#pragma unroll
    for (int a = 0; a < cA; a++) {
        ushort4v hv = *(const ushort4v*)&ha[(size_t)a * cL];
        ushort4v tv = *(const ushort4v*)&ta[(size_t)a * cL];
#pragma unroll
        for (int i = 0; i < 4; i++) v[i] += bf2f(hv[i]) * bf2f(tv[i]);
    }
    float psum = 0.f;
#pragma unroll
    for (int i = 0; i < 4; i++) { v[i] *= (1.0f / cA); psum += v[i]; }
    for (int off = 32; off > 0; off >>= 1) psum += __shfl_down(psum, off, 64);
    __shared__ float red[4];
    if ((tid & 63) == 0) red[tid >> 6] = psum;
    __syncthreads();
    float tot = red[0] + red[1] + red[2] + red[3];
    float inv = 1.0f / (tot + 1e-5f);
    ushort4v o;
#pragma unroll
    for (int i = 0; i < 4; i++) o[i] = f2bf(v[i] * inv);
    *(ushort4v*)&w[(size_t)nr * cL + l0] = o;
}

// ---------------------------------------------------------------------------
// Kernel 4: rel MFMA GEMM: rel[n][h] = sum_l w[n][l] * seqT[b][h][l]
__global__ __launch_bounds__(256) void
rel_mfma_k(const ushort* __restrict__ wbf, const ushort* __restrict__ seqT,
           ushort* __restrict__ relbf) {
    const int b = blockIdx.z;
    const int r0 = blockIdx.x * 128, h0 = blockIdx.y * 64;
    const int tid = threadIdx.x, lane = tid & 63, wv = tid >> 6;
    const int col = lane & 15, g = lane >> 4;

    __shared__ ushort sA[128 * 72];
    __shared__ ushort sB[64 * 72];

    float4v acc[2][4];
#pragma unroll
    for (int mt = 0; mt < 2; mt++)
#pragma unroll
        for (int ct = 0; ct < 4; ct++) acc[mt][ct] = (float4v){0.f, 0.f, 0.f, 0.f};

    for (int kt = 0; kt < cL; kt += 64) {
#pragma unroll
        for (int p = 0; p < 4; p++) {
            int t = tid + p * 256;
            int row = t >> 3, seg = t & 7;
            int r = min(r0 + row, cR - 1);
            *(short8*)&sA[row * 72 + seg * 8] =
                *(const short8*)&wbf[((size_t)b * cR + r) * cL + kt + seg * 8];
        }
#pragma unroll
        for (int p = 0; p < 2; p++) {
            int t = tid + p * 256;
            int c = t >> 3, seg = t & 7;
            *(short8*)&sB[c * 72 + seg * 8] =
                *(const short8*)&seqT[((size_t)b * cH + h0 + c) * cL + kt + seg * 8];
        }
        __syncthreads();
        const int wrow = wv * 32;
#pragma unroll
        for (int k0 = 0; k0 < 64; k0 += 32) {
            short8 a0 = *(const short8*)&sA[(wrow + col) * 72 + k0 + g * 8];
            short8 a1 = *(const short8*)&sA[(wrow + 16 + col) * 72 + k0 + g * 8];
#pragma unroll
            for (int ct = 0; ct < 4; ct++) {
                short8 bf = *(const short8*)&sB[(ct * 16 + col) * 72 + k0 + g * 8];
                acc[0][ct] = __builtin_amdgcn_mfma_f32_16x16x32_bf16(a0, bf, acc[0][ct], 0, 0, 0);
                acc[1][ct] = __builtin_amdgcn_mfma_f32_16x16x32_bf16(a1, bf, acc[1][ct], 0, 0, 0);
            }
        }
        __syncthreads();
    }
#pragma unroll
    for (int mt = 0; mt < 2; mt++) {
#pragma unroll
        for (int ct = 0; ct < 4; ct++) {
            int h = h0 + ct * 16 + col;
            int rowb = r0 + wv * 32 + mt * 16 + g * 4;
#pragma unroll
            for (int reg = 0; reg < 4; reg++) {
                int r = rowb + reg;
                if (r < cR)
                    relbf[((size_t)b * cR + r) * cH + h] = f2bf(acc[mt][ct][reg]);
            }
        }
    }
}

// ---------------------------------------------------------------------------
// Kernel 5: projection MFMA GEMM, head+tail fused (blockIdx.z = sel).
__global__ __launch_bounds__(256) void
proj_mfma_k(const ushort* __restrict__ ent_bf, const ushort* __restrict__ relbf,
            const int* __restrict__ hts,
            const ushort* __restrict__ WTh, const ushort* __restrict__ WTt,
            const float* __restrict__ head_b, const float* __restrict__ tail_b,
            ushort* __restrict__ hsp, ushort* __restrict__ tsp) {
    const int sel = blockIdx.z;
    const ushort* WTp = sel ? WTt : WTh;
    const float* bias = sel ? tail_b : head_b;
    ushort* outp = sel ? tsp : hsp;

    const int n0 = blockIdx.x * 64, e0 = blockIdx.y * 64;
    const int tid = threadIdx.x, lane = tid & 63, wv = tid >> 6;
    const int col = lane & 15, g = lane >> 4;

    __shared__ int sbase[64];
    __shared__ ushort sA[64 * 72];
    __shared__ ushort sB[64 * 72];

    if (tid < 64) {
        int n = n0 + tid, bb = n / cR;
        sbase[tid] = (bb * cE + hts[n * 2 + sel]) * cH;
    }
    __syncthreads();

    float4v acc[4];
#pragma unroll
    for (int ct = 0; ct < 4; ct++) acc[ct] = (float4v){0.f, 0.f, 0.f, 0.f};

    for (int kt = 0; kt < 2 * cH; kt += 64) {
        const bool first = kt < cH;
#pragma unroll
        for (int p = 0; p < 2; p++) {
            int t = tid + p * 256;
            int row = t >> 3, seg = t & 7;
            const ushort* src = first
                ? &ent_bf[(size_t)sbase[row] + kt + seg * 8]
                : &relbf[(size_t)(n0 + row) * cH + (kt - cH) + seg * 8];
            *(short8*)&sA[row * 72 + seg * 8] = *(const short8*)src;
        }
#pragma unroll
        for (int p = 0; p < 2; p++) {
            int t = tid + p * 256;
            int c = t >> 3, seg = t & 7;
            *(short8*)&sB[c * 72 + seg * 8] =
                *(const short8*)&WTp[(size_t)(e0 + c) * (2 * cH) + kt + seg * 8];
        }
        __syncthreads();
        const int wrow = wv * 16;
#pragma unroll
        for (int k0 = 0; k0 < 64; k0 += 32) {
            short8 a0 = *(const short8*)&sA[(wrow + col) * 72 + k0 + g * 8];
#pragma unroll
            for (int ct = 0; ct < 4; ct++) {
                short8 bf = *(const short8*)&sB[(ct * 16 + col) * 72 + k0 + g * 8];
                acc[ct] = __builtin_amdgcn_mfma_f32_16x16x32_bf16(a0, bf, acc[ct], 0, 0, 0);
            }
        }
        __syncthreads();
    }
#pragma unroll
    for (int ct = 0; ct < 4; ct++) {
        int e = e0 + ct * 16 + col;
        float bv = bias[e];
        int rowb = n0 + wv * 16 + g * 4;
#pragma unroll
        for (int reg = 0; reg < 4; reg++)
            outp[(size_t)(rowb + reg) * cEMB + e] = f2bf(tanhf(acc[ct][reg] + bv));
    }
}

// ---------------------------------------------------------------------------
// Kernel 6: bilinear v11 — BARRIER-FREE inner loop, W from L2-resident global
// into registers.
// Post-mortem v8/v9/v10: per-step time pinned at ~2700 cyc across register-W,
// LDS-W, and 5-deep counted-vmcnt schedules; extra waves (v8, ~12/CU) gave
// zero per-CU throughput gain; all pipes sit at ~20%. Common residue: the
// per-step s_barrier lockstep needed solely to recycle shared sW LDS slots —
// it serializes every step's LDS phase against every wave's compute phase.
// v11: grp = blockIdx.x keeps block_id%8 = grp, pinning each 1.5 MB Wf slice
// to one XCD's L2 (v9's accidental win). W-frags are loaded straight from
// L2-resident global into registers with an unroll-2 double buffer (~350 cyc
// of cover vs ~220 cyc L2 latency). No sW, no DMA, no per-step barrier:
// the 32-step inner loop has zero sync. n-tile 64 (grid 8x62, ~2 blocks/CU)
// so 2-3 independent waves/SIMD fill residual stalls. Numerics identical.
__global__ __launch_bounds__(256) void
bil_mfma11_k(const ushort* __restrict__ hsp, const ushort* __restrict__ tsp,
             const ushort* __restrict__ Wf, float* __restrict__ part) {
    const int grp = blockIdx.x;          // 0..7 -> islices 3g..3g+2 (XCD-pinned)
    const int n0 = blockIdx.y * 64;
    const int tid = threadIdx.x;
    const int lane = tid & 63, wv = tid >> 6;   // wv = column-quad 0..3
    const int col = lane & 15, g4 = lane >> 4;

    __shared__ float sHs[32 * 68];       // [i][row], stride 68 keeps 16B align

    float4v acc[4][2];
#pragma unroll
    for (int mt = 0; mt < 4; mt++)
#pragma unroll
        for (int ctl = 0; ctl < 2; ctl++) acc[mt][ctl] = (float4v){0.f, 0.f, 0.f, 0.f};

    // 96 consecutive 16KB (8192-ushort) W i-blocks for this group
    const ushort* WfG = Wf + (size_t)grp * 3 * 32 * 8192;
    // this wave's fragment base: f = kh*8 + wv*2 + ctl, elem ((f*64)+lane)*8
    const ushort* wbase = WfG + ((size_t)(wv * 2) * 64 + lane) * 8;

    // load the 4 W-frags (kh x ctl) of step t into a register buffer
#define WLOAD(dst, t) {                                                        \
        const ushort* _p = wbase + (size_t)(t) * 8192;                         \
        dst[0][0] = *(const short8*)&_p[0];                                    \
        dst[0][1] = *(const short8*)&_p[512];                                  \
        dst[1][0] = *(const short8*)&_p[4096];                                 \
        dst[1][1] = *(const short8*)&_p[4608];                                 \
    }

#define BILSTEP(ii, w) {                                                       \
        float4v hsv[4];                                                        \
        _Pragma("unroll")                                                      \
        for (int mt = 0; mt < 4; mt++)                                         \
            hsv[mt] = *(const float4v*)&sHs[(ii) * 68 + mt * 16 + g4 * 4];     \
        _Pragma("unroll")                                                      \
        for (int ctl = 0; ctl < 2; ctl++) {                                    \
            _Pragma("unroll")                                                  \
            for (int mt = 0; mt < 4; mt++) {                                   \
                float4v P = (float4v){0.f, 0.f, 0.f, 0.f};                     \
                P = __builtin_amdgcn_mfma_f32_16x16x32_bf16(tsA[mt][0], w[0][ctl], P, 0, 0, 0); \
                P = __builtin_amdgcn_mfma_f32_16x16x32_bf16(tsA[mt][1], w[1][ctl], P, 0, 0, 0); \
                acc[mt][ctl] += hsv[mt] * P;                                   \
            }                                                                  \
        }                                                                      \
    }

    short8 tsA[4][2];
    short8 wA[2][2], wB[2][2];
    WLOAD(wA, 0);

    for (int s = 0; s < 3; ++s) {
        const int islice = grp * 3 + s;
        const int kb = islice >> 1;

        __syncthreads();   // previous islice's sHs readers done
        {
            // stage hs: 64 rows x 32 i, one short8 per thread
            int row = tid & 63, seg = tid >> 6;
            short8 v = *(const short8*)
                &hsp[(size_t)(n0 + row) * cEMB + islice * 32 + seg * 8];
#pragma unroll
            for (int jj = 0; jj < 8; jj++)
                sHs[(seg * 8 + jj) * 68 + row] = bf2f((ushort)v[jj]);
        }
        // ts A-fragments for this islice (registers, live for 32 steps)
#pragma unroll
        for (int mt = 0; mt < 4; mt++)
#pragma unroll
            for (int kh = 0; kh < 2; kh++)
                tsA[mt][kh] = *(const short8*)
                    &tsp[(size_t)(n0 + mt * 16 + col) * cEMB
                         + kb * 64 + kh * 32 + g4 * 8];
        __syncthreads();   // sHs visible

        // barrier-free inner loop, unroll-2 register double buffer on W
        for (int i = 0; i < 32; i += 2) {
            const int t = s * 32 + i;
            WLOAD(wB, t + 1);
            BILSTEP(i, wA);
            if (t + 2 < 96) WLOAD(wA, t + 2);
            BILSTEP(i + 1, wB);
        }
    }
#undef WLOAD
#undef BILSTEP

    // epilogue: plain coalesced f32 stores (c padded to 128; c>=97 is junk
    // the reduce kernel never reads)
    float* pbase = part + (size_t)grp * cN * 128;
#pragma unroll
    for (int mt = 0; mt < 4; mt++) {
#pragma unroll
        for (int ctl = 0; ctl < 2; ctl++) {
            int c = (wv * 2 + ctl) * 16 + col;
            int rowb = n0 + mt * 16 + g4 * 4;
#pragma unroll
            for (int reg = 0; reg < 4; reg++)
                pbase[(size_t)(rowb + reg) * 128 + c] = acc[mt][ctl][reg];
        }
    }
}

// ---------------------------------------------------------------------------
// Kernel 7: reduce 8 partials + bias -> out (replaces out_init + atomics)
__global__ void bil_reduce_k(const float* __restrict__ part,
                             const float* __restrict__ bil_b,
                             float* __restrict__ out) {
    int n = blockIdx.x;
    int c = threadIdx.x;            // 128 threads, c >= cC inactive
    if (c >= cC) return;
    float s = bil_b[c];
#pragma unroll
    for (int g = 0; g < cNG; g++)
        s += part[((size_t)g * cN + n) * 128 + c];
    out[(size_t)n * cC + c] = s;
}

// ---------------------------------------------------------------------------
extern "C" void kernel_launch(void* const* d_in, const int* in_sizes, int n_in,
                              void* d_out, int out_size, void* d_ws, size_t ws_size,
                              hipStream_t stream) {
    const float* seq_lhs  = (const float*)d_in[0];
    const float* ent_lhs  = (const float*)d_in[1];
    const float* attn     = (const float*)d_in[2];
    const int*   ids      = (const int*)d_in[3];
    const int*   hts      = (const int*)d_in[4];
    const float* head_W   = (const float*)d_in[5];
    const float* head_b   = (const float*)d_in[6];
    const float* tail_W   = (const float*)d_in[7];
    const float* tail_b   = (const float*)d_in[8];
    const float* bil_W    = (const float*)d_in[9];
    const float* bil_b    = (const float*)d_in[10];
    float* out = (float*)d_out;

    // workspace layout (byte offsets, 256B-aligned)
    char* ws = (char*)d_ws;
    int*    counts   = (int*)(ws + 0);             // 512 B
    ushort* ent_bf   = (ushort*)(ws + 512);        // 262144 B
    ushort* ent_attn = (ushort*)(ws + 262656);     // bf16, 4194304 B
    ushort* wbuf     = (ushort*)(ws + 4456960);    // 8126464 B
    ushort* relbf    = (ushort*)(ws + 12583424);   // 8126464 B
    ushort* hsp      = (ushort*)(ws + 20709888);   // 6094848 B
    ushort* tsp      = (ushort*)(ws + 26804736);   // 6094848 B
    ushort* Wf       = (ushort*)(ws + 32899584);   // 12582912 B
    ushort* WTh      = (ushort*)(ws + 45482496);   // 3145728 B
    ushort* WTt      = (ushort*)(ws + 48628224);   // 3145728 B
    ushort* seqT     = (ushort*)(ws + 51773952);   // 8388608 B  (end 60162560)
    // bilinear partials: 8 x 3968 x 128 x f32 = 16252928 B, overlaid on the
    // stream-dead ent_attn/wbuf/relbf region (all consumed before bil launch)
    float*  part     = (float*)(ws + 262656);

    hipLaunchKernelGGL(wf_build_k, dim3(768), dim3(256), 0, stream, bil_W, Wf);
    hipLaunchKernelGGL(tr_ht_k, dim3(64, 24, 2), dim3(256), 0, stream,
                       head_W, tail_W, WTh, WTt);
    hipLaunchKernelGGL(tr_bf16_k, dim3(32, 32, cB), dim3(256), 0, stream,
                       seq_lhs, seqT, cL, cH, cH);

    hipLaunchKernelGGL(ent_pool_k, dim3(cE, cB, 4), dim3(256), 0, stream,
                       ent_lhs, ids, ent_bf, counts);
    hipLaunchKernelGGL(ent_attn_k, dim3(cB * cA, cL / 256), dim3(256), 0, stream,
                       attn, ids, counts, ent_attn);
    hipLaunchKernelGGL(w_k, dim3(cN), dim3(256), 0, stream,
                       ent_attn, hts, wbuf);
    hipLaunchKernelGGL(rel_mfma_k, dim3(8, 16, cB), dim3(256), 0, stream,
                       wbuf, seqT, relbf);
    hipLaunchKernelGGL(proj_mfma_k, dim3(cN / 64, cEMB / 64, 2), dim3(256), 0, stream,
                       ent_bf, relbf, hts, WTh, WTt, head_b, tail_b, hsp, tsp);
    hipLaunchKernelGGL(bil_mfma11_k, dim3(cNG, cN / 64), dim3(256), 0, stream,
                       hsp, tsp, Wf, part);
    hipLaunchKernelGGL(bil_reduce_k, dim3(cN), dim3(128), 0, stream,
                       part, bil_b, out);
}

// Round 5
// 322.522 us; speedup vs baseline: 1.3015x; 1.0778x over previous
//
#include <hip/hip_runtime.h>
#include <hip/hip_bf16.h>
#include <math.h>

// Problem constants
constexpr int cB   = 4;
constexpr int cL   = 1024;
constexpr int cH   = 1024;
constexpr int cA   = 16;
constexpr int cM   = 128;
constexpr int cE   = 32;
constexpr int cR   = 992;
constexpr int cEMB = 768;
constexpr int cC   = 97;
constexpr int cN   = cB * cR;   // 3968
constexpr int cNG  = 8;         // islice groups (3 islices each)

typedef unsigned short ushort;
typedef __attribute__((ext_vector_type(4))) unsigned short ushort4v;
typedef __attribute__((ext_vector_type(8))) short short8;
typedef __attribute__((ext_vector_type(4))) float float4v;

static __device__ inline float bf2f(ushort u) {
    unsigned v = ((unsigned)u) << 16;
    float f;
    __builtin_memcpy(&f, &v, 4);
    return f;
}
static __device__ inline ushort f2bf(float f) {
    unsigned u;
    __builtin_memcpy(&u, &f, 4);
    unsigned r = (u + 0x7FFFu + ((u >> 16) & 1u)) >> 16;
    return (ushort)r;
}

// 16B global -> LDS DMA (LDS dest: wave-uniform base + lane*16)
static __device__ inline void gld16(const ushort* src, ushort* dstbase) {
    __builtin_amdgcn_global_load_lds(
        (const __attribute__((address_space(1))) unsigned int*)src,
        (__attribute__((address_space(3))) unsigned int*)dstbase, 16, 0, 0);
}

// ---------------------------------------------------------------------------
// Generic transpose f32 -> bf16: src[z][R][C] -> dst[z][Cp][R], zero-pad c>=C
__global__ void tr_bf16_k(const float* __restrict__ src, ushort* __restrict__ dst,
                          int R, int C, int Cp) {
    int z = blockIdx.z;
    int r0 = blockIdx.x * 32, c0 = blockIdx.y * 32;
    int tx = threadIdx.x & 31, ty = threadIdx.x >> 5;  // ty 0..7
    __shared__ float tile[32][33];
    for (int p = 0; p < 4; p++) {
        int r = r0 + ty + p * 8, c = c0 + tx;
        tile[ty + p * 8][tx] = (r < R && c < C) ? src[((size_t)z * R + r) * C + c] : 0.f;
    }
    __syncthreads();
    for (int p = 0; p < 4; p++) {
        int c = c0 + ty + p * 8, r = r0 + tx;
        if (c < Cp && r < R)
            dst[((size_t)z * Cp + c) * R + r] = f2bf(tile[tx][ty + p * 8]);
    }
}

// Head+tail weight transpose in one launch (z selects which matrix)
__global__ void tr_ht_k(const float* __restrict__ Wh, const float* __restrict__ Wt,
                        ushort* __restrict__ WTh, ushort* __restrict__ WTt) {
    const float* src = blockIdx.z ? Wt : Wh;
    ushort* dst = blockIdx.z ? WTt : WTh;
    int r0 = blockIdx.x * 32, c0 = blockIdx.y * 32;
    int tx = threadIdx.x & 31, ty = threadIdx.x >> 5;
    __shared__ float tile[32][33];
    for (int p = 0; p < 4; p++) {
        int r = r0 + ty + p * 8, c = c0 + tx;
        tile[ty + p * 8][tx] = src[(size_t)r * cEMB + c];
    }
    __syncthreads();
    for (int p = 0; p < 4; p++) {
        int c = c0 + ty + p * 8, r = r0 + tx;
        dst[(size_t)c * (2 * cH) + r] = f2bf(tile[tx][ty + p * 8]);
    }
}

// ---------------------------------------------------------------------------
// Build fragment-ordered bilinear weights (16 frags per i, v3 layout):
// Wf[si][f][lane][8] bf16, f = khalf*8+ct,
// element = W[(si*64 + j)][c], j = khalf*32 + (lane>>4)*8 + jj, c = ct*16 + (lane&15)
__global__ void wf_build_k(const float* __restrict__ W, ushort* __restrict__ Wf) {
    const int si = blockIdx.x;
    const int tid = threadIdx.x;
    __shared__ ushort sWb[64 * 136];
    for (int idx = tid; idx < 64 * 128; idx += 256) {
        int r = idx >> 7, c = idx & 127;
        float v = (c < cC) ? W[((size_t)si * 64 + r) * cC + c] : 0.f;
        sWb[r * 136 + c] = f2bf(v);
    }
    __syncthreads();
#pragma unroll
    for (int p = 0; p < 4; p++) {
        int e = tid + p * 256;          // 0..1023
        int f = e >> 6, lane = e & 63;
        int g = lane >> 4, col = lane & 15;
        int khalf = f >> 3, ct = f & 7;
        int jb = khalf * 32 + g * 8;
        int c = ct * 16 + col;
        short8 v;
#pragma unroll
        for (int jj = 0; jj < 8; jj++) v[jj] = (short)sWb[(jb + jj) * 136 + c];
        *(short8*)&Wf[(((size_t)si * 16 + f) * 64 + lane) * 8] = v;
    }
}

// ---------------------------------------------------------------------------
// Kernel 1: per-(b,e) logsumexp pooling of ent_lhs; writes bf16.
__global__ void ent_pool_k(const float* __restrict__ ent_lhs, const int* __restrict__ ids,
                           ushort* __restrict__ ent_emb, int* __restrict__ counts) {
    int e = blockIdx.x, b = blockIdx.y;
    __shared__ int sid[cM];
    int tid = threadIdx.x;
    if (tid < cM) sid[tid] = ids[b * cM + tid];
    __syncthreads();
    int cnt = 0;
    for (int m = 0; m < cM; m++) cnt += (sid[m] == e) ? 1 : 0;
    if (blockIdx.z == 0 && tid == 0) counts[b * cE + e] = cnt;
    int h = blockIdx.z * 256 + tid;
    {
        float mx = -1e30f;
        for (int m = 0; m < cM; m++)
            if (sid[m] == e) mx = fmaxf(mx, ent_lhs[(size_t)(b * cM + m) * cH + h]);
        float s = 0.f;
        for (int m = 0; m < cM; m++)
            if (sid[m] == e) s += __expf(ent_lhs[(size_t)(b * cM + m) * cH + h] - mx);
        ent_emb[(size_t)(b * cE + e) * cH + h] = f2bf((cnt > 0) ? (mx + __logf(s)) : 0.f);
    }
}

// ---------------------------------------------------------------------------
// Kernel 2: ent_attn[b][e][a][l] (bf16) = segment-mean of attn
__global__ void ent_attn_k(const float* __restrict__ attn, const int* __restrict__ ids,
                           const int* __restrict__ counts, ushort* __restrict__ ent_attn) {
    int ba = blockIdx.x;
    int b = ba / cA, a = ba % cA;
    int tid = threadIdx.x;
    int l = blockIdx.y * 256 + tid;
    __shared__ int sid[cM];
    __shared__ int scnt[cE];
    __shared__ float sacc[256 * 33];
    if (tid < cM) sid[tid] = ids[b * cM + tid];
    if (tid < cE) scnt[tid] = counts[b * cE + tid];
    float* acc = &sacc[tid * 33];
    for (int e2 = 0; e2 < cE; e2++) acc[e2] = 0.f;
    __syncthreads();
    const float* ap = attn + ((size_t)(b * cA + a) * cM) * cL + l;
    for (int m = 0; m < cM; m++) acc[sid[m]] += ap[(size_t)m * cL];
    for (int e2 = 0; e2 < cE; e2++) {
        ent_attn[((size_t)(b * cE + e2) * cA + a) * cL + l] =
            f2bf(acc[e2] / (float)max(scnt[e2], 1));
    }
}

// ---------------------------------------------------------------------------
// Kernel 3: w[b][r][l] = mean_a ha*ta, normalized over l (ushort4 vectorized)
__global__ void w_k(const ushort* __restrict__ ent_attn, const int* __restrict__ hts,
                    ushort* __restrict__ w) {
    int nr = blockIdx.x;
    int b = nr / cR;
    int he = hts[nr * 2 + 0], te = hts[nr * 2 + 1];
    int tid = threadIdx.x;
    int l0 = tid * 4;
    const ushort* ha = ent_attn + ((size_t)(b * cE + he) * cA) * cL + l0;
    const ushort* ta = ent_attn + ((size_t)(b * cE + te) * cA) * cL + l0;
    float v[4] = {0.f, 0.f, 0.f, 0.f};
#pragma unroll
    for (int a = 0; a < cA; a++) {
        ushort4v hv = *(const ushort4v*)&ha[(size_t)a * cL];
        ushort4v tv = *(const ushort4v*)&ta[(size_t)a * cL];
#pragma unroll
        for (int i = 0; i < 4; i++) v[i] += bf2f(hv[i]) * bf2f(tv[i]);
    }
    float psum = 0.f;
#pragma unroll
    for (int i = 0; i < 4; i++) { v[i] *= (1.0f / cA); psum += v[i]; }
    for (int off = 32; off > 0; off >>= 1) psum += __shfl_down(psum, off, 64);
    __shared__ float red[4];
    if ((tid & 63) == 0) red[tid >> 6] = psum;
    __syncthreads();
    float tot = red[0] + red[1] + red[2] + red[3];
    float inv = 1.0f / (tot + 1e-5f);
    ushort4v o;
#pragma unroll
    for (int i = 0; i < 4; i++) o[i] = f2bf(v[i] * inv);
    *(ushort4v*)&w[(size_t)nr * cL + l0] = o;
}

// ---------------------------------------------------------------------------
// Kernel 4: rel MFMA GEMM: rel[n][h] = sum_l w[n][l] * seqT[b][h][l]
__global__ __launch_bounds__(256) void
rel_mfma_k(const ushort* __restrict__ wbf, const ushort* __restrict__ seqT,
           ushort* __restrict__ relbf) {
    const int b = blockIdx.z;
    const int r0 = blockIdx.x * 128, h0 = blockIdx.y * 64;
    const int tid = threadIdx.x, lane = tid & 63, wv = tid >> 6;
    const int col = lane & 15, g = lane >> 4;

    __shared__ ushort sA[128 * 72];
    __shared__ ushort sB[64 * 72];

    float4v acc[2][4];
#pragma unroll
    for (int mt = 0; mt < 2; mt++)
#pragma unroll
        for (int ct = 0; ct < 4; ct++) acc[mt][ct] = (float4v){0.f, 0.f, 0.f, 0.f};

    for (int kt = 0; kt < cL; kt += 64) {
#pragma unroll
        for (int p = 0; p < 4; p++) {
            int t = tid + p * 256;
            int row = t >> 3, seg = t & 7;
            int r = min(r0 + row, cR - 1);
            *(short8*)&sA[row * 72 + seg * 8] =
                *(const short8*)&wbf[((size_t)b * cR + r) * cL + kt + seg * 8];
        }
#pragma unroll
        for (int p = 0; p < 2; p++) {
            int t = tid + p * 256;
            int c = t >> 3, seg = t & 7;
            *(short8*)&sB[c * 72 + seg * 8] =
                *(const short8*)&seqT[((size_t)b * cH + h0 + c) * cL + kt + seg * 8];
        }
        __syncthreads();
        const int wrow = wv * 32;
#pragma unroll
        for (int k0 = 0; k0 < 64; k0 += 32) {
            short8 a0 = *(const short8*)&sA[(wrow + col) * 72 + k0 + g * 8];
            short8 a1 = *(const short8*)&sA[(wrow + 16 + col) * 72 + k0 + g * 8];
#pragma unroll
            for (int ct = 0; ct < 4; ct++) {
                short8 bf = *(const short8*)&sB[(ct * 16 + col) * 72 + k0 + g * 8];
                acc[0][ct] = __builtin_amdgcn_mfma_f32_16x16x32_bf16(a0, bf, acc[0][ct], 0, 0, 0);
                acc[1][ct] = __builtin_amdgcn_mfma_f32_16x16x32_bf16(a1, bf, acc[1][ct], 0, 0, 0);
            }
        }
        __syncthreads();
    }
#pragma unroll
    for (int mt = 0; mt < 2; mt++) {
#pragma unroll
        for (int ct = 0; ct < 4; ct++) {
            int h = h0 + ct * 16 + col;
            int rowb = r0 + wv * 32 + mt * 16 + g * 4;
#pragma unroll
            for (int reg = 0; reg < 4; reg++) {
                int r = rowb + reg;
                if (r < cR)
                    relbf[((size_t)b * cR + r) * cH + h] = f2bf(acc[mt][ct][reg]);
            }
        }
    }
}

// ---------------------------------------------------------------------------
// Kernel 5: projection MFMA GEMM v2, head+tail fused (blockIdx.z = sel).
// Post-mortem of v1 (70.6 µs): FETCH 99.5 MB vs ~14.5 MB unique inputs
// (relbf re-fetched 24x: 12 e-blocks x 2 sel, with grid-x=n so no L2 window
// for relbf rows); 7.6M LDS bank-conflict cycles (stride-36-dword *72 pad:
// ds_write_b128 lands 8 lanes/bank); 16x64 wave tile = 8 MFMA per 10
// ds_reads. v2: BM=64 x BN=128, wave tile 32x64 (2x4 frags, 16 MFMA / 12
// ds_reads per step); staging via global_load_lds width=16 with rule-#21
// both-sides XOR swizzle (linear LDS dest, pre-swizzled per-lane global
// source seg' = seg^(row&7), swizzled ds_read) -> conflict-free; grid-x =
// e-block so consecutive blocks share n0 and relbf rows come from L2/L3.
// Gathered ent_bf rows work because gload_lds's GLOBAL address is per-lane.
__global__ __launch_bounds__(256) void
proj_mfma2_k(const ushort* __restrict__ ent_bf, const ushort* __restrict__ relbf,
             const int* __restrict__ hts,
             const ushort* __restrict__ WTh, const ushort* __restrict__ WTt,
             const float* __restrict__ head_b, const float* __restrict__ tail_b,
             ushort* __restrict__ hsp, ushort* __restrict__ tsp) {
    const int sel = blockIdx.z;
    const ushort* WTp = sel ? WTt : WTh;
    const float* bias = sel ? tail_b : head_b;
    ushort* outp = sel ? tsp : hsp;

    const int e0 = blockIdx.x * 128, n0 = blockIdx.y * 64;
    const int tid = threadIdx.x, lane = tid & 63, wv = tid >> 6;
    const int col = lane & 15, g4 = lane >> 4;
    const int wr = wv >> 1, wc = wv & 1;   // wave tile: rows [wr*32,+32), cols [wc*64,+64)

    __shared__ ushort sA[64 * 64];    // [row][64], seg-swizzled content
    __shared__ ushort sB[128 * 64];

    // staging lane geometry: lane covers rows {base + lane>>3}, seg lane&7,
    // source seg pre-swizzled so linear LDS + swizzled read are consistent
    const int lr = lane >> 3;              // 0..7
    const int swz = (lane & 7) ^ lr;       // (row&7) == lr for all staged rows

    // A row sources (rows ra0 = wv*8+lr, ra1 = ra0+32)
    const int ra0 = wv * 8 + lr, ra1 = ra0 + 32;
    size_t eb0, eb1;
    { int n = n0 + ra0, bb = n / cR; eb0 = ((size_t)(bb * cE + hts[n * 2 + sel])) * cH; }
    { int n = n0 + ra1, bb = n / cR; eb1 = ((size_t)(bb * cE + hts[n * 2 + sel])) * cH; }
    const ushort* aent0 = ent_bf + eb0 + swz * 8;
    const ushort* aent1 = ent_bf + eb1 + swz * 8;
    const ushort* arel0 = relbf + (size_t)(n0 + ra0) * cH + swz * 8;
    const ushort* arel1 = relbf + (size_t)(n0 + ra1) * cH + swz * 8;

    // B row sources (rows c = p*32 + wv*8 + lr)
    const ushort* bptr[4];
#pragma unroll
    for (int p = 0; p < 4; p++)
        bptr[p] = WTp + (size_t)(e0 + p * 32 + wv * 8 + lr) * (2 * cH) + swz * 8;

    float4v acc[2][4];
#pragma unroll
    for (int mt = 0; mt < 2; mt++)
#pragma unroll
        for (int ct = 0; ct < 4; ct++) acc[mt][ct] = (float4v){0.f, 0.f, 0.f, 0.f};

    for (int kt = 0; kt < 2 * cH; kt += 64) {
        const bool first = kt < cH;
        const ushort* a0 = first ? aent0 + kt : arel0 + (kt - cH);
        const ushort* a1 = first ? aent1 + kt : arel1 + (kt - cH);
        gld16(a0, &sA[(0 * 4 + wv) * 512]);
        gld16(a1, &sA[(1 * 4 + wv) * 512]);
#pragma unroll
        for (int p = 0; p < 4; p++)
            gld16(bptr[p] + kt, &sB[(p * 4 + wv) * 512]);
        __syncthreads();   // vmcnt(0) drained before barrier -> tiles landed

#pragma unroll
        for (int k0 = 0; k0 < 64; k0 += 32) {
            short8 av[2];
#pragma unroll
            for (int mt = 0; mt < 2; mt++) {
                int ra = wr * 32 + mt * 16 + col;
                int sg = ((k0 >> 3) + g4) ^ (ra & 7);
                av[mt] = *(const short8*)&sA[ra * 64 + sg * 8];
            }
#pragma unroll
            for (int ct = 0; ct < 4; ct++) {
                int rb = wc * 64 + ct * 16 + col;
                int sg = ((k0 >> 3) + g4) ^ (rb & 7);
                short8 bv = *(const short8*)&sB[rb * 64 + sg * 8];
#pragma unroll
                for (int mt = 0; mt < 2; mt++)
                    acc[mt][ct] = __builtin_amdgcn_mfma_f32_16x16x32_bf16(
                        av[mt], bv, acc[mt][ct], 0, 0, 0);
            }
        }
        __syncthreads();   // readers done before next staging overwrites
    }

#pragma unroll
    for (int mt = 0; mt < 2; mt++) {
#pragma unroll
        for (int ct = 0; ct < 4; ct++) {
            int e = e0 + wc * 64 + ct * 16 + col;
            float bv = bias[e];
            int rowb = n0 + wr * 32 + mt * 16 + g4 * 4;
#pragma unroll
            for (int reg = 0; reg < 4; reg++)
                outp[(size_t)(rowb + reg) * cEMB + e] = f2bf(tanhf(acc[mt][ct][reg] + bv));
        }
    }
}

// ---------------------------------------------------------------------------
// Kernel 6: bilinear v11 — BARRIER-FREE inner loop, W from L2-resident global
// into registers. (Round-3 verified: removed per-step barrier lockstep.)
__global__ __launch_bounds__(256) void
bil_mfma11_k(const ushort* __restrict__ hsp, const ushort* __restrict__ tsp,
             const ushort* __restrict__ Wf, float* __restrict__ part) {
    const int grp = blockIdx.x;          // 0..7 -> islices 3g..3g+2 (XCD-pinned)
    const int n0 = blockIdx.y * 64;
    const int tid = threadIdx.x;
    const int lane = tid & 63, wv = tid >> 6;   // wv = column-quad 0..3
    const int col = lane & 15, g4 = lane >> 4;

    __shared__ float sHs[32 * 68];       // [i][row], stride 68 keeps 16B align

    float4v acc[4][2];
#pragma unroll
    for (int mt = 0; mt < 4; mt++)
#pragma unroll
        for (int ctl = 0; ctl < 2; ctl++) acc[mt][ctl] = (float4v){0.f, 0.f, 0.f, 0.f};

    // 96 consecutive 16KB (8192-ushort) W i-blocks for this group
    const ushort* WfG = Wf + (size_t)grp * 3 * 32 * 8192;
    // this wave's fragment base: f = kh*8 + wv*2 + ctl, elem ((f*64)+lane)*8
    const ushort* wbase = WfG + ((size_t)(wv * 2) * 64 + lane) * 8;

#define WLOAD(dst, t) {                                                        \
        const ushort* _p = wbase + (size_t)(t) * 8192;                         \
        dst[0][0] = *(const short8*)&_p[0];                                    \
        dst[0][1] = *(const short8*)&_p[512];                                  \
        dst[1][0] = *(const short8*)&_p[4096];                                 \
        dst[1][1] = *(const short8*)&_p[4608];                                 \
    }

#define BILSTEP(ii, w) {                                                       \
        float4v hsv[4];                                                        \
        _Pragma("unroll")                                                      \
        for (int mt = 0; mt < 4; mt++)                                         \
            hsv[mt] = *(const float4v*)&sHs[(ii) * 68 + mt * 16 + g4 * 4];     \
        _Pragma("unroll")                                                      \
        for (int ctl = 0; ctl < 2; ctl++) {                                    \
            _Pragma("unroll")                                                  \
            for (int mt = 0; mt < 4; mt++) {                                   \
                float4v P = (float4v){0.f, 0.f, 0.f, 0.f};                     \
                P = __builtin_amdgcn_mfma_f32_16x16x32_bf16(tsA[mt][0], w[0][ctl], P, 0, 0, 0); \
                P = __builtin_amdgcn_mfma_f32_16x16x32_bf16(tsA[mt][1], w[1][ctl], P, 0, 0, 0); \
                acc[mt][ctl] += hsv[mt] * P;                                   \
            }                                                                  \
        }                                                                      \
    }

    short8 tsA[4][2];
    short8 wA[2][2], wB[2][2];
    WLOAD(wA, 0);

    for (int s = 0; s < 3; ++s) {
        const int islice = grp * 3 + s;
        const int kb = islice >> 1;

        __syncthreads();   // previous islice's sHs readers done
        {
            // stage hs: 64 rows x 32 i, one short8 per thread
            int row = tid & 63, seg = tid >> 6;
            short8 v = *(const short8*)
                &hsp[(size_t)(n0 + row) * cEMB + islice * 32 + seg * 8];
#pragma unroll
            for (int jj = 0; jj < 8; jj++)
                sHs[(seg * 8 + jj) * 68 + row] = bf2f((ushort)v[jj]);
        }
        // ts A-fragments for this islice (registers, live for 32 steps)
#pragma unroll
        for (int mt = 0; mt < 4; mt++)
#pragma unroll
            for (int kh = 0; kh < 2; kh++)
                tsA[mt][kh] = *(const short8*)
                    &tsp[(size_t)(n0 + mt * 16 + col) * cEMB
                         + kb * 64 + kh * 32 + g4 * 8];
        __syncthreads();   // sHs visible

        // barrier-free inner loop, unroll-2 register double buffer on W
        for (int i = 0; i < 32; i += 2) {
            const int t = s * 32 + i;
            WLOAD(wB, t + 1);
            BILSTEP(i, wA);
            if (t + 2 < 96) WLOAD(wA, t + 2);
            BILSTEP(i + 1, wB);
        }
    }
#undef WLOAD
#undef BILSTEP

    // epilogue: plain coalesced f32 stores (c padded to 128; c>=97 is junk
    // the reduce kernel never reads)
    float* pbase = part + (size_t)grp * cN * 128;
#pragma unroll
    for (int mt = 0; mt < 4; mt++) {
#pragma unroll
        for (int ctl = 0; ctl < 2; ctl++) {
            int c = (wv * 2 + ctl) * 16 + col;
            int rowb = n0 + mt * 16 + g4 * 4;
#pragma unroll
            for (int reg = 0; reg < 4; reg++)
                pbase[(size_t)(rowb + reg) * 128 + c] = acc[mt][ctl][reg];
        }
    }
}

// ---------------------------------------------------------------------------
// Kernel 7: reduce 8 partials + bias -> out (replaces out_init + atomics)
__global__ void bil_reduce_k(const float* __restrict__ part,
                             const float* __restrict__ bil_b,
                             float* __restrict__ out) {
    int n = blockIdx.x;
    int c = threadIdx.x;            // 128 threads, c >= cC inactive
    if (c >= cC) return;
    float s = bil_b[c];
#pragma unroll
    for (int g = 0; g < cNG; g++)
        s += part[((size_t)g * cN + n) * 128 + c];
    out[(size_t)n * cC + c] = s;
}

// ---------------------------------------------------------------------------
extern "C" void kernel_launch(void* const* d_in, const int* in_sizes, int n_in,
                              void* d_out, int out_size, void* d_ws, size_t ws_size,
                              hipStream_t stream) {
    const float* seq_lhs  = (const float*)d_in[0];
    const float* ent_lhs  = (const float*)d_in[1];
    const float* attn     = (const float*)d_in[2];
    const int*   ids      = (const int*)d_in[3];
    const int*   hts      = (const int*)d_in[4];
    const float* head_W   = (const float*)d_in[5];
    const float* head_b   = (const float*)d_in[6];
    const float* tail_W   = (const float*)d_in[7];
    const float* tail_b   = (const float*)d_in[8];
    const float* bil_W    = (const float*)d_in[9];
    const float* bil_b    = (const float*)d_in[10];
    float* out = (float*)d_out;

    // workspace layout (byte offsets, 256B-aligned)
    char* ws = (char*)d_ws;
    int*    counts   = (int*)(ws + 0);             // 512 B
    ushort* ent_bf   = (ushort*)(ws + 512);        // 262144 B
    ushort* ent_attn = (ushort*)(ws + 262656);     // bf16, 4194304 B
    ushort* wbuf     = (ushort*)(ws + 4456960);    // 8126464 B
    ushort* relbf    = (ushort*)(ws + 12583424);   // 8126464 B
    ushort* hsp      = (ushort*)(ws + 20709888);   // 6094848 B
    ushort* tsp      = (ushort*)(ws + 26804736);   // 6094848 B
    ushort* Wf       = (ushort*)(ws + 32899584);   // 12582912 B
    ushort* WTh      = (ushort*)(ws + 45482496);   // 3145728 B
    ushort* WTt      = (ushort*)(ws + 48628224);   // 3145728 B
    ushort* seqT     = (ushort*)(ws + 51773952);   // 8388608 B  (end 60162560)
    // bilinear partials: 8 x 3968 x 128 x f32 = 16252928 B, overlaid on the
    // stream-dead ent_attn/wbuf/relbf region (all consumed before bil launch)
    float*  part     = (float*)(ws + 262656);

    hipLaunchKernelGGL(wf_build_k, dim3(768), dim3(256), 0, stream, bil_W, Wf);
    hipLaunchKernelGGL(tr_ht_k, dim3(64, 24, 2), dim3(256), 0, stream,
                       head_W, tail_W, WTh, WTt);
    hipLaunchKernelGGL(tr_bf16_k, dim3(32, 32, cB), dim3(256), 0, stream,
                       seq_lhs, seqT, cL, cH, cH);

    hipLaunchKernelGGL(ent_pool_k, dim3(cE, cB, 4), dim3(256), 0, stream,
                       ent_lhs, ids, ent_bf, counts);
    hipLaunchKernelGGL(ent_attn_k, dim3(cB * cA, cL / 256), dim3(256), 0, stream,
                       attn, ids, counts, ent_attn);
    hipLaunchKernelGGL(w_k, dim3(cN), dim3(256), 0, stream,
                       ent_attn, hts, wbuf);
    hipLaunchKernelGGL(rel_mfma_k, dim3(8, 16, cB), dim3(256), 0, stream,
                       wbuf, seqT, relbf);
    hipLaunchKernelGGL(proj_mfma2_k, dim3(cEMB / 128, cN / 64, 2), dim3(256), 0, stream,
                       ent_bf, relbf, hts, WTh, WTt, head_b, tail_b, hsp, tsp);
    hipLaunchKernelGGL(bil_mfma11_k, dim3(cNG, cN / 64), dim3(256), 0, stream,
                       hsp, tsp, Wf, part);
    hipLaunchKernelGGL(bil_reduce_k, dim3(cN), dim3(128), 0, stream,
                       part, bil_b, out);
}

// Round 6
// 312.641 us; speedup vs baseline: 1.3426x; 1.0316x over previous
//
#include <hip/hip_runtime.h>
#include <hip/hip_bf16.h>
#include <math.h>

// Problem constants
constexpr int cB   = 4;
constexpr int cL   = 1024;
constexpr int cH   = 1024;
constexpr int cA   = 16;
constexpr int cM   = 128;
constexpr int cE   = 32;
constexpr int cR   = 992;
constexpr int cEMB = 768;
constexpr int cC   = 97;
constexpr int cN   = cB * cR;   // 3968
constexpr int cNG  = 8;         // islice groups (3 islices each)

typedef unsigned short ushort;
typedef __attribute__((ext_vector_type(4))) unsigned short ushort4v;
typedef __attribute__((ext_vector_type(8))) short short8;
typedef __attribute__((ext_vector_type(4))) float float4v;

static __device__ inline float bf2f(ushort u) {
    unsigned v = ((unsigned)u) << 16;
    float f;
    __builtin_memcpy(&f, &v, 4);
    return f;
}
static __device__ inline ushort f2bf(float f) {
    unsigned u;
    __builtin_memcpy(&u, &f, 4);
    unsigned r = (u + 0x7FFFu + ((u >> 16) & 1u)) >> 16;
    return (ushort)r;
}

// 16B global -> LDS DMA (LDS dest: wave-uniform base + lane*16)
static __device__ inline void gld16(const ushort* src, ushort* dstbase) {
    __builtin_amdgcn_global_load_lds(
        (const __attribute__((address_space(1))) unsigned int*)src,
        (__attribute__((address_space(3))) unsigned int*)dstbase, 16, 0, 0);
}

// ---------------------------------------------------------------------------
// Generic transpose f32 -> bf16: src[z][R][C] -> dst[z][Cp][R], zero-pad c>=C
__global__ void tr_bf16_k(const float* __restrict__ src, ushort* __restrict__ dst,
                          int R, int C, int Cp) {
    int z = blockIdx.z;
    int r0 = blockIdx.x * 32, c0 = blockIdx.y * 32;
    int tx = threadIdx.x & 31, ty = threadIdx.x >> 5;  // ty 0..7
    __shared__ float tile[32][33];
    for (int p = 0; p < 4; p++) {
        int r = r0 + ty + p * 8, c = c0 + tx;
        tile[ty + p * 8][tx] = (r < R && c < C) ? src[((size_t)z * R + r) * C + c] : 0.f;
    }
    __syncthreads();
    for (int p = 0; p < 4; p++) {
        int c = c0 + ty + p * 8, r = r0 + tx;
        if (c < Cp && r < R)
            dst[((size_t)z * Cp + c) * R + r] = f2bf(tile[tx][ty + p * 8]);
    }
}

// Head+tail weight transpose in one launch (z selects which matrix)
__global__ void tr_ht_k(const float* __restrict__ Wh, const float* __restrict__ Wt,
                        ushort* __restrict__ WTh, ushort* __restrict__ WTt) {
    const float* src = blockIdx.z ? Wt : Wh;
    ushort* dst = blockIdx.z ? WTt : WTh;
    int r0 = blockIdx.x * 32, c0 = blockIdx.y * 32;
    int tx = threadIdx.x & 31, ty = threadIdx.x >> 5;
    __shared__ float tile[32][33];
    for (int p = 0; p < 4; p++) {
        int r = r0 + ty + p * 8, c = c0 + tx;
        tile[ty + p * 8][tx] = src[(size_t)r * cEMB + c];
    }
    __syncthreads();
    for (int p = 0; p < 4; p++) {
        int c = c0 + ty + p * 8, r = r0 + tx;
        dst[(size_t)c * (2 * cH) + r] = f2bf(tile[tx][ty + p * 8]);
    }
}

// ---------------------------------------------------------------------------
// Build fragment-ordered bilinear weights (16 frags per i, v3 layout):
// Wf[si][f][lane][8] bf16, f = khalf*8+ct,
// element = W[(si*64 + j)][c], j = khalf*32 + (lane>>4)*8 + jj, c = ct*16 + (lane&15)
__global__ void wf_build_k(const float* __restrict__ W, ushort* __restrict__ Wf) {
    const int si = blockIdx.x;
    const int tid = threadIdx.x;
    __shared__ ushort sWb[64 * 136];
    for (int idx = tid; idx < 64 * 128; idx += 256) {
        int r = idx >> 7, c = idx & 127;
        float v = (c < cC) ? W[((size_t)si * 64 + r) * cC + c] : 0.f;
        sWb[r * 136 + c] = f2bf(v);
    }
    __syncthreads();
#pragma unroll
    for (int p = 0; p < 4; p++) {
        int e = tid + p * 256;          // 0..1023
        int f = e >> 6, lane = e & 63;
        int g = lane >> 4, col = lane & 15;
        int khalf = f >> 3, ct = f & 7;
        int jb = khalf * 32 + g * 8;
        int c = ct * 16 + col;
        short8 v;
#pragma unroll
        for (int jj = 0; jj < 8; jj++) v[jj] = (short)sWb[(jb + jj) * 136 + c];
        *(short8*)&Wf[(((size_t)si * 16 + f) * 64 + lane) * 8] = v;
    }
}

// ---------------------------------------------------------------------------
// Kernel 1: per-(b,e) logsumexp pooling of ent_lhs; writes bf16.
__global__ void ent_pool_k(const float* __restrict__ ent_lhs, const int* __restrict__ ids,
                           ushort* __restrict__ ent_emb, int* __restrict__ counts) {
    int e = blockIdx.x, b = blockIdx.y;
    __shared__ int sid[cM];
    int tid = threadIdx.x;
    if (tid < cM) sid[tid] = ids[b * cM + tid];
    __syncthreads();
    int cnt = 0;
    for (int m = 0; m < cM; m++) cnt += (sid[m] == e) ? 1 : 0;
    if (blockIdx.z == 0 && tid == 0) counts[b * cE + e] = cnt;
    int h = blockIdx.z * 256 + tid;
    {
        float mx = -1e30f;
        for (int m = 0; m < cM; m++)
            if (sid[m] == e) mx = fmaxf(mx, ent_lhs[(size_t)(b * cM + m) * cH + h]);
        float s = 0.f;
        for (int m = 0; m < cM; m++)
            if (sid[m] == e) s += __expf(ent_lhs[(size_t)(b * cM + m) * cH + h] - mx);
        ent_emb[(size_t)(b * cE + e) * cH + h] = f2bf((cnt > 0) ? (mx + __logf(s)) : 0.f);
    }
}

// ---------------------------------------------------------------------------
// Kernel 2: ent_attn[b][e][a][l] (bf16) = segment-mean of attn
__global__ void ent_attn_k(const float* __restrict__ attn, const int* __restrict__ ids,
                           const int* __restrict__ counts, ushort* __restrict__ ent_attn) {
    int ba = blockIdx.x;
    int b = ba / cA, a = ba % cA;
    int tid = threadIdx.x;
    int l = blockIdx.y * 256 + tid;
    __shared__ int sid[cM];
    __shared__ int scnt[cE];
    __shared__ float sacc[256 * 33];
    if (tid < cM) sid[tid] = ids[b * cM + tid];
    if (tid < cE) scnt[tid] = counts[b * cE + tid];
    float* acc = &sacc[tid * 33];
    for (int e2 = 0; e2 < cE; e2++) acc[e2] = 0.f;
    __syncthreads();
    const float* ap = attn + ((size_t)(b * cA + a) * cM) * cL + l;
    for (int m = 0; m < cM; m++) acc[sid[m]] += ap[(size_t)m * cL];
    for (int e2 = 0; e2 < cE; e2++) {
        ent_attn[((size_t)(b * cE + e2) * cA + a) * cL + l] =
            f2bf(acc[e2] / (float)max(scnt[e2], 1));
    }
}

// ---------------------------------------------------------------------------
// Kernel 3: w[b][r][l] = mean_a ha*ta, normalized over l (ushort4 vectorized)
__global__ void w_k(const ushort* __restrict__ ent_attn, const int* __restrict__ hts,
                    ushort* __restrict__ w) {
    int nr = blockIdx.x;
    int b = nr / cR;
    int he = hts[nr * 2 + 0], te = hts[nr * 2 + 1];
    int tid = threadIdx.x;
    int l0 = tid * 4;
    const ushort* ha = ent_attn + ((size_t)(b * cE + he) * cA) * cL + l0;
    const ushort* ta = ent_attn + ((size_t)(b * cE + te) * cA) * cL + l0;
    float v[4] = {0.f, 0.f, 0.f, 0.f};
#pragma unroll
    for (int a = 0; a < cA; a++) {
        ushort4v hv = *(const ushort4v*)&ha[(size_t)a * cL];
        ushort4v tv = *(const ushort4v*)&ta[(size_t)a * cL];
#pragma unroll
        for (int i = 0; i < 4; i++) v[i] += bf2f(hv[i]) * bf2f(tv[i]);
    }
    float psum = 0.f;
#pragma unroll
    for (int i = 0; i < 4; i++) { v[i] *= (1.0f / cA); psum += v[i]; }
    for (int off = 32; off > 0; off >>= 1) psum += __shfl_down(psum, off, 64);
    __shared__ float red[4];
    if ((tid & 63) == 0) red[tid >> 6] = psum;
    __syncthreads();
    float tot = red[0] + red[1] + red[2] + red[3];
    float inv = 1.0f / (tot + 1e-5f);
    ushort4v o;
#pragma unroll
    for (int i = 0; i < 4; i++) o[i] = f2bf(v[i] * inv);
    *(ushort4v*)&w[(size_t)nr * cL + l0] = o;
}

// ---------------------------------------------------------------------------
// Kernel 4: rel MFMA GEMM v2: rel[n][h] = sum_l w[n][l] * seqT[b][h][l].
// Port of the proj2 structure (verified Round 4): v1 had the *72-pad LDS
// staging (8-way quad bank conflict on ds_write_b128 — proj v1 measured 7.6M
// conflict cycles on this exact layout) and VGPR round-trip staging.
// v2: gld16 width-16 DMA, rule-#21 both-sides XOR swizzle, 32x64 wave tile,
// + T3 minimum-2-phase double buffer: STAGE(t+1) issued BEFORE compute(t),
// ONE barrier per K-step (compiler drains vmcnt(0) at the barrier -> stage
// latency hides under the 16 MFMA). Rows >= cR: source clamped, store skipped.
__global__ __launch_bounds__(256) void
rel_mfma2_k(const ushort* __restrict__ wbf, const ushort* __restrict__ seqT,
            ushort* __restrict__ relbf) {
    const int b = blockIdx.z;
    const int h0 = blockIdx.x * 128, r0 = blockIdx.y * 64;
    const int tid = threadIdx.x, lane = tid & 63, wv = tid >> 6;
    const int col = lane & 15, g4 = lane >> 4;
    const int wr = wv >> 1, wc = wv & 1;   // wave tile rows [wr*32,+32) cols [wc*64,+64)

    __shared__ ushort sA[2][64 * 64];
    __shared__ ushort sB[2][128 * 64];

    const int lr = lane >> 3;              // 0..7
    const int swz = (lane & 7) ^ lr;       // source seg pre-swizzle

    // A sources: wbuf rows (clamped)
    const int ra0 = wv * 8 + lr, ra1 = ra0 + 32;
    const ushort* a0p = wbf + ((size_t)b * cR + min(r0 + ra0, cR - 1)) * cL + swz * 8;
    const ushort* a1p = wbf + ((size_t)b * cR + min(r0 + ra1, cR - 1)) * cL + swz * 8;
    // B sources: seqT rows h = h0 + p*32 + wv*8 + lr
    const ushort* bptr[4];
#pragma unroll
    for (int p = 0; p < 4; p++)
        bptr[p] = seqT + ((size_t)b * cH + h0 + p * 32 + wv * 8 + lr) * cL + swz * 8;

    float4v acc[2][4];
#pragma unroll
    for (int mt = 0; mt < 2; mt++)
#pragma unroll
        for (int ct = 0; ct < 4; ct++) acc[mt][ct] = (float4v){0.f, 0.f, 0.f, 0.f};

#define REL_STAGE(kt, buf) {                                                   \
        gld16(a0p + (kt), &sA[buf][wv * 512]);                                 \
        gld16(a1p + (kt), &sA[buf][(4 + wv) * 512]);                           \
        _Pragma("unroll")                                                      \
        for (int p = 0; p < 4; p++)                                            \
            gld16(bptr[p] + (kt), &sB[buf][(p * 4 + wv) * 512]);               \
    }

    REL_STAGE(0, 0);
    __syncthreads();   // vmcnt(0) drained at barrier -> tile 0 landed
    int cur = 0;
    for (int kt = 0; kt < cL; kt += 64) {
        if (kt + 64 < cL) REL_STAGE(kt + 64, cur ^ 1);
#pragma unroll
        for (int k0 = 0; k0 < 64; k0 += 32) {
            short8 av[2];
#pragma unroll
            for (int mt = 0; mt < 2; mt++) {
                int ra = wr * 32 + mt * 16 + col;
                int sg = ((k0 >> 3) + g4) ^ (ra & 7);
                av[mt] = *(const short8*)&sA[cur][ra * 64 + sg * 8];
            }
#pragma unroll
            for (int ct = 0; ct < 4; ct++) {
                int rb = wc * 64 + ct * 16 + col;
                int sg = ((k0 >> 3) + g4) ^ (rb & 7);
                short8 bv = *(const short8*)&sB[cur][rb * 64 + sg * 8];
#pragma unroll
                for (int mt = 0; mt < 2; mt++)
                    acc[mt][ct] = __builtin_amdgcn_mfma_f32_16x16x32_bf16(
                        av[mt], bv, acc[mt][ct], 0, 0, 0);
            }
        }
        __syncthreads();   // readers done with cur; prefetch (cur^1) landed
        cur ^= 1;
    }
#undef REL_STAGE

#pragma unroll
    for (int mt = 0; mt < 2; mt++) {
#pragma unroll
        for (int ct = 0; ct < 4; ct++) {
            int h = h0 + wc * 64 + ct * 16 + col;
            int rowb = r0 + wr * 32 + mt * 16 + g4 * 4;
#pragma unroll
            for (int reg = 0; reg < 4; reg++) {
                int r = rowb + reg;
                if (r < cR)
                    relbf[((size_t)b * cR + r) * cH + h] = f2bf(acc[mt][ct][reg]);
            }
        }
    }
}

// ---------------------------------------------------------------------------
// Kernel 5: projection MFMA GEMM v3 = v2 (Round-4 verified: gld16 + XOR
// swizzle + e-major grid) + T3 minimum-2-phase double buffer: STAGE(t+1)
// before compute(t), ONE barrier per K-step instead of two (the per-step
// vmcnt(0)-drain-then-compute serialization was the remaining structural
// stall; m248v2 isolated +10% for this exact change).
__global__ __launch_bounds__(256) void
proj_mfma3_k(const ushort* __restrict__ ent_bf, const ushort* __restrict__ relbf,
             const int* __restrict__ hts,
             const ushort* __restrict__ WTh, const ushort* __restrict__ WTt,
             const float* __restrict__ head_b, const float* __restrict__ tail_b,
             ushort* __restrict__ hsp, ushort* __restrict__ tsp) {
    const int sel = blockIdx.z;
    const ushort* WTp = sel ? WTt : WTh;
    const float* bias = sel ? tail_b : head_b;
    ushort* outp = sel ? tsp : hsp;

    const int e0 = blockIdx.x * 128, n0 = blockIdx.y * 64;
    const int tid = threadIdx.x, lane = tid & 63, wv = tid >> 6;
    const int col = lane & 15, g4 = lane >> 4;
    const int wr = wv >> 1, wc = wv & 1;

    __shared__ ushort sA[2][64 * 64];
    __shared__ ushort sB[2][128 * 64];

    const int lr = lane >> 3;
    const int swz = (lane & 7) ^ lr;

    const int ra0 = wv * 8 + lr, ra1 = ra0 + 32;
    size_t eb0, eb1;
    { int n = n0 + ra0, bb = n / cR; eb0 = ((size_t)(bb * cE + hts[n * 2 + sel])) * cH; }
    { int n = n0 + ra1, bb = n / cR; eb1 = ((size_t)(bb * cE + hts[n * 2 + sel])) * cH; }
    const ushort* aent0 = ent_bf + eb0 + swz * 8;
    const ushort* aent1 = ent_bf + eb1 + swz * 8;
    const ushort* arel0 = relbf + (size_t)(n0 + ra0) * cH + swz * 8;
    const ushort* arel1 = relbf + (size_t)(n0 + ra1) * cH + swz * 8;

    const ushort* bptr[4];
#pragma unroll
    for (int p = 0; p < 4; p++)
        bptr[p] = WTp + (size_t)(e0 + p * 32 + wv * 8 + lr) * (2 * cH) + swz * 8;

    float4v acc[2][4];
#pragma unroll
    for (int mt = 0; mt < 2; mt++)
#pragma unroll
        for (int ct = 0; ct < 4; ct++) acc[mt][ct] = (float4v){0.f, 0.f, 0.f, 0.f};

#define PROJ_STAGE(kt, buf) {                                                  \
        const ushort* a0 = ((kt) < cH) ? aent0 + (kt) : arel0 + ((kt) - cH);   \
        const ushort* a1 = ((kt) < cH) ? aent1 + (kt) : arel1 + ((kt) - cH);   \
        gld16(a0, &sA[buf][wv * 512]);                                         \
        gld16(a1, &sA[buf][(4 + wv) * 512]);                                   \
        _Pragma("unroll")                                                      \
        for (int p = 0; p < 4; p++)                                            \
            gld16(bptr[p] + (kt), &sB[buf][(p * 4 + wv) * 512]);               \
    }

    PROJ_STAGE(0, 0);
    __syncthreads();
    int cur = 0;
    for (int kt = 0; kt < 2 * cH; kt += 64) {
        if (kt + 64 < 2 * cH) PROJ_STAGE(kt + 64, cur ^ 1);
#pragma unroll
        for (int k0 = 0; k0 < 64; k0 += 32) {
            short8 av[2];
#pragma unroll
            for (int mt = 0; mt < 2; mt++) {
                int ra = wr * 32 + mt * 16 + col;
                int sg = ((k0 >> 3) + g4) ^ (ra & 7);
                av[mt] = *(const short8*)&sA[cur][ra * 64 + sg * 8];
            }
#pragma unroll
            for (int ct = 0; ct < 4; ct++) {
                int rb = wc * 64 + ct * 16 + col;
                int sg = ((k0 >> 3) + g4) ^ (rb & 7);
                short8 bv = *(const short8*)&sB[cur][rb * 64 + sg * 8];
#pragma unroll
                for (int mt = 0; mt < 2; mt++)
                    acc[mt][ct] = __builtin_amdgcn_mfma_f32_16x16x32_bf16(
                        av[mt], bv, acc[mt][ct], 0, 0, 0);
            }
        }
        __syncthreads();
        cur ^= 1;
    }
#undef PROJ_STAGE

#pragma unroll
    for (int mt = 0; mt < 2; mt++) {
#pragma unroll
        for (int ct = 0; ct < 4; ct++) {
            int e = e0 + wc * 64 + ct * 16 + col;
            float bv = bias[e];
            int rowb = n0 + wr * 32 + mt * 16 + g4 * 4;
#pragma unroll
            for (int reg = 0; reg < 4; reg++)
                outp[(size_t)(rowb + reg) * cEMB + e] = f2bf(tanhf(acc[mt][ct][reg] + bv));
        }
    }
}

// ---------------------------------------------------------------------------
// Kernel 6: bilinear v11 — barrier-free inner loop (Round-3 verified) +
// s_setprio around the MFMA cluster (T5). bil's waves are independent and
// phase-staggered — the attn-like regime where setprio paid +4-7% (m191),
// not the lockstep-GEMM regime where it was null (m190).
__global__ __launch_bounds__(256) void
bil_mfma11_k(const ushort* __restrict__ hsp, const ushort* __restrict__ tsp,
             const ushort* __restrict__ Wf, float* __restrict__ part) {
    const int grp = blockIdx.x;          // 0..7 -> islices 3g..3g+2 (XCD-pinned)
    const int n0 = blockIdx.y * 64;
    const int tid = threadIdx.x;
    const int lane = tid & 63, wv = tid >> 6;   // wv = column-quad 0..3
    const int col = lane & 15, g4 = lane >> 4;

    __shared__ float sHs[32 * 68];       // [i][row], stride 68 keeps 16B align

    float4v acc[4][2];
#pragma unroll
    for (int mt = 0; mt < 4; mt++)
#pragma unroll
        for (int ctl = 0; ctl < 2; ctl++) acc[mt][ctl] = (float4v){0.f, 0.f, 0.f, 0.f};

    // 96 consecutive 16KB (8192-ushort) W i-blocks for this group
    const ushort* WfG = Wf + (size_t)grp * 3 * 32 * 8192;
    // this wave's fragment base: f = kh*8 + wv*2 + ctl, elem ((f*64)+lane)*8
    const ushort* wbase = WfG + ((size_t)(wv * 2) * 64 + lane) * 8;

#define WLOAD(dst, t) {                                                        \
        const ushort* _p = wbase + (size_t)(t) * 8192;                         \
        dst[0][0] = *(const short8*)&_p[0];                                    \
        dst[0][1] = *(const short8*)&_p[512];                                  \
        dst[1][0] = *(const short8*)&_p[4096];                                 \
        dst[1][1] = *(const short8*)&_p[4608];                                 \
    }

#define BILSTEP(ii, w) {                                                       \
        float4v hsv[4];                                                        \
        _Pragma("unroll")                                                      \
        for (int mt = 0; mt < 4; mt++)                                         \
            hsv[mt] = *(const float4v*)&sHs[(ii) * 68 + mt * 16 + g4 * 4];     \
        __builtin_amdgcn_s_setprio(1);                                         \
        _Pragma("unroll")                                                      \
        for (int ctl = 0; ctl < 2; ctl++) {                                    \
            _Pragma("unroll")                                                  \
            for (int mt = 0; mt < 4; mt++) {                                   \
                float4v P = (float4v){0.f, 0.f, 0.f, 0.f};                     \
                P = __builtin_amdgcn_mfma_f32_16x16x32_bf16(tsA[mt][0], w[0][ctl], P, 0, 0, 0); \
                P = __builtin_amdgcn_mfma_f32_16x16x32_bf16(tsA[mt][1], w[1][ctl], P, 0, 0, 0); \
                acc[mt][ctl] += hsv[mt] * P;                                   \
            }                                                                  \
        }                                                                      \
        __builtin_amdgcn_s_setprio(0);                                         \
    }

    short8 tsA[4][2];
    short8 wA[2][2], wB[2][2];
    WLOAD(wA, 0);

    for (int s = 0; s < 3; ++s) {
        const int islice = grp * 3 + s;
        const int kb = islice >> 1;

        __syncthreads();   // previous islice's sHs readers done
        {
            // stage hs: 64 rows x 32 i, one short8 per thread
            int row = tid & 63, seg = tid >> 6;
            short8 v = *(const short8*)
                &hsp[(size_t)(n0 + row) * cEMB + islice * 32 + seg * 8];
#pragma unroll
            for (int jj = 0; jj < 8; jj++)
                sHs[(seg * 8 + jj) * 68 + row] = bf2f((ushort)v[jj]);
        }
        // ts A-fragments for this islice (registers, live for 32 steps)
#pragma unroll
        for (int mt = 0; mt < 4; mt++)
#pragma unroll
            for (int kh = 0; kh < 2; kh++)
                tsA[mt][kh] = *(const short8*)
                    &tsp[(size_t)(n0 + mt * 16 + col) * cEMB
                         + kb * 64 + kh * 32 + g4 * 8];
        __syncthreads();   // sHs visible

        // barrier-free inner loop, unroll-2 register double buffer on W
        for (int i = 0; i < 32; i += 2) {
            const int t = s * 32 + i;
            WLOAD(wB, t + 1);
            BILSTEP(i, wA);
            if (t + 2 < 96) WLOAD(wA, t + 2);
            BILSTEP(i + 1, wB);
        }
    }
#undef WLOAD
#undef BILSTEP

    // epilogue: plain coalesced f32 stores (c padded to 128; c>=97 is junk
    // the reduce kernel never reads)
    float* pbase = part + (size_t)grp * cN * 128;
#pragma unroll
    for (int mt = 0; mt < 4; mt++) {
#pragma unroll
        for (int ctl = 0; ctl < 2; ctl++) {
            int c = (wv * 2 + ctl) * 16 + col;
            int rowb = n0 + mt * 16 + g4 * 4;
#pragma unroll
            for (int reg = 0; reg < 4; reg++)
                pbase[(size_t)(rowb + reg) * 128 + c] = acc[mt][ctl][reg];
        }
    }
}

// ---------------------------------------------------------------------------
// Kernel 7: reduce 8 partials + bias -> out (replaces out_init + atomics)
__global__ void bil_reduce_k(const float* __restrict__ part,
                             const float* __restrict__ bil_b,
                             float* __restrict__ out) {
    int n = blockIdx.x;
    int c = threadIdx.x;            // 128 threads, c >= cC inactive
    if (c >= cC) return;
    float s = bil_b[c];
#pragma unroll
    for (int g = 0; g < cNG; g++)
        s += part[((size_t)g * cN + n) * 128 + c];
    out[(size_t)n * cC + c] = s;
}

// ---------------------------------------------------------------------------
extern "C" void kernel_launch(void* const* d_in, const int* in_sizes, int n_in,
                              void* d_out, int out_size, void* d_ws, size_t ws_size,
                              hipStream_t stream) {
    const float* seq_lhs  = (const float*)d_in[0];
    const float* ent_lhs  = (const float*)d_in[1];
    const float* attn     = (const float*)d_in[2];
    const int*   ids      = (const int*)d_in[3];
    const int*   hts      = (const int*)d_in[4];
    const float* head_W   = (const float*)d_in[5];
    const float* head_b   = (const float*)d_in[6];
    const float* tail_W   = (const float*)d_in[7];
    const float* tail_b   = (const float*)d_in[8];
    const float* bil_W    = (const float*)d_in[9];
    const float* bil_b    = (const float*)d_in[10];
    float* out = (float*)d_out;

    // workspace layout (byte offsets, 256B-aligned)
    char* ws = (char*)d_ws;
    int*    counts   = (int*)(ws + 0);             // 512 B
    ushort* ent_bf   = (ushort*)(ws + 512);        // 262144 B
    ushort* ent_attn = (ushort*)(ws + 262656);     // bf16, 4194304 B
    ushort* wbuf     = (ushort*)(ws + 4456960);    // 8126464 B
    ushort* relbf    = (ushort*)(ws + 12583424);   // 8126464 B
    ushort* hsp      = (ushort*)(ws + 20709888);   // 6094848 B
    ushort* tsp      = (ushort*)(ws + 26804736);   // 6094848 B
    ushort* Wf       = (ushort*)(ws + 32899584);   // 12582912 B
    ushort* WTh      = (ushort*)(ws + 45482496);   // 3145728 B
    ushort* WTt      = (ushort*)(ws + 48628224);   // 3145728 B
    ushort* seqT     = (ushort*)(ws + 51773952);   // 8388608 B  (end 60162560)
    // bilinear partials: 8 x 3968 x 128 x f32 = 16252928 B, overlaid on the
    // stream-dead ent_attn/wbuf/relbf region (all consumed before bil launch)
    float*  part     = (float*)(ws + 262656);

    hipLaunchKernelGGL(wf_build_k, dim3(768), dim3(256), 0, stream, bil_W, Wf);
    hipLaunchKernelGGL(tr_ht_k, dim3(64, 24, 2), dim3(256), 0, stream,
                       head_W, tail_W, WTh, WTt);
    hipLaunchKernelGGL(tr_bf16_k, dim3(32, 32, cB), dim3(256), 0, stream,
                       seq_lhs, seqT, cL, cH, cH);

    hipLaunchKernelGGL(ent_pool_k, dim3(cE, cB, 4), dim3(256), 0, stream,
                       ent_lhs, ids, ent_bf, counts);
    hipLaunchKernelGGL(ent_attn_k, dim3(cB * cA, cL / 256), dim3(256), 0, stream,
                       attn, ids, counts, ent_attn);
    hipLaunchKernelGGL(w_k, dim3(cN), dim3(256), 0, stream,
                       ent_attn, hts, wbuf);
    hipLaunchKernelGGL(rel_mfma2_k, dim3(cH / 128, 16, cB), dim3(256), 0, stream,
                       wbuf, seqT, relbf);
    hipLaunchKernelGGL(proj_mfma3_k, dim3(cEMB / 128, cN / 64, 2), dim3(256), 0, stream,
                       ent_bf, relbf, hts, WTh, WTt, head_b, tail_b, hsp, tsp);
    hipLaunchKernelGGL(bil_mfma11_k, dim3(cNG, cN / 64), dim3(256), 0, stream,
                       hsp, tsp, Wf, part);
    hipLaunchKernelGGL(bil_reduce_k, dim3(cN), dim3(128), 0, stream,
                       part, bil_b, out);
}